// Round 5
// baseline (281.040 us; speedup 1.0000x reference)
//
#include <hip/hip_runtime.h>

#define SEQ 2048
#define HID 2048
#define NH  32
#define NKV 8
#define HD  64

typedef _Float16 f16;
typedef __attribute__((ext_vector_type(4))) _Float16 f16x4;
typedef __attribute__((ext_vector_type(8))) _Float16 f16x8;
typedef __attribute__((ext_vector_type(4))) float    f32x4;

__device__ __forceinline__ f32x4 mfma_16x16x32(f16x8 a, f16x8 b, f32x4 c) {
    return __builtin_amdgcn_mfma_f32_16x16x32_f16(a, b, c, 0, 0, 0);
}

// async global->LDS, 16B per lane. Global address is PER-LANE (gather);
// LDS dest is wave-uniform base + lane*16 (contiguous).
__device__ __forceinline__ void async16(const void* g, void* l) {
    __builtin_amdgcn_global_load_lds(
        (const __attribute__((address_space(1))) void*)g,
        (__attribute__((address_space(3))) void*)l,
        16, 0, 0);
}

// ---------------- prep kernels ----------------

__global__ void cvt_f32_to_f16(const float* __restrict__ src, f16* __restrict__ dst) {
    int i = (blockIdx.x * 256 + threadIdx.x) * 4;
    float4 v = *(const float4*)(src + i);
    f16x4 o = { (f16)v.x, (f16)v.y, (f16)v.z, (f16)v.w };
    *(f16x4*)(dst + i) = o;
}

// All four weight transposes in one launch; route by blockIdx.z.
// dst[c][r] = (f16)src[r][c];  R = 2048 rows for all.
__global__ void transpose_all(const float* __restrict__ wq, const float* __restrict__ wk,
                              const float* __restrict__ wv, const float* __restrict__ wo,
                              f16* __restrict__ Wcat, f16* __restrict__ woT) {
    __shared__ float tile[32][33];
    int z = blockIdx.z;
    const float* src; f16* dst; int C;
    if      (z == 0) { src = wq; dst = Wcat;                         C = 2048; }
    else if (z == 1) { src = wk; dst = Wcat + (size_t)2048 * 2048;   C = 512;  }
    else if (z == 2) { src = wv; dst = Wcat + (size_t)2560 * 2048;   C = 512;  }
    else             { src = wo; dst = woT;                          C = 2048; }
    int c0 = blockIdx.x * 32, r0 = blockIdx.y * 32;
    if (c0 >= C) return;
    int tx = threadIdx.x, ty = threadIdx.y;
#pragma unroll
    for (int i = 0; i < 32; i += 8)
        tile[ty + i][tx] = src[(size_t)(r0 + ty + i) * C + c0 + tx];
    __syncthreads();
#pragma unroll
    for (int i = 0; i < 32; i += 8)
        dst[(size_t)(c0 + ty + i) * 2048 + r0 + tx] = (f16)tile[tx][ty + i];
}

// ---------------- GEMM: C[M,N] = A[M,K] @ BT[N,K]^T ----------------
// 128(M) x 64(N) tile, BK=32, 4 waves as 4x1 (wave w: rows w*32..+31, all 64 n).
// Single-barrier double-buffered LDS staging (prefetch in flight during compute).
// MODE 0: fused QKV epilogue with RoPE: n0<2048 -> Q (RoPE, scaled 1/8*log2e);
//         n0<2560 -> K (RoPE); else -> V^T passthrough (f16x4 stores).
// MODE 2: fp32 row-major into Cf.
template <int MODE>
__global__ __launch_bounds__(256)
void gemm_bt(const f16* __restrict__ A, const f16* __restrict__ BT,
             float* __restrict__ Cf, f16* __restrict__ Q, f16* __restrict__ Kk,
             f16* __restrict__ VT, const int* __restrict__ pos, int N, int K) {
    __shared__ f16 As[2 * 128 * 32];
    __shared__ f16 Bs[2 * 64 * 32];
    int t = threadIdx.x;
    int w = t >> 6, lane = t & 63, quad = lane >> 4, l15 = lane & 15;
    int m0 = blockIdx.y * 128, n0 = blockIdx.x * 64;

    int srow  = t >> 2;        // 0..63
    int skoff = (t & 3) * 8;
    const f16* Ag = A  + (size_t)(m0 + srow) * K + skoff;
    const f16* Bg = BT + (size_t)(n0 + srow) * K + skoff;

    f32x4 acc[2][4] = {};

    // stage tile 0
    async16(Ag,                  As + w * 512);
    async16(Ag + (size_t)64 * K, As + 2048 + w * 512);
    async16(Bg,                  Bs + w * 512);
    __syncthreads();

    int b = 0;
    for (int kt = 32; kt <= K; kt += 32) {
        if (kt < K) {   // prefetch next tile into buf b^1
            async16(Ag + kt,                  As + (b ^ 1) * 4096 + w * 512);
            async16(Ag + (size_t)64 * K + kt, As + (b ^ 1) * 4096 + 2048 + w * 512);
            async16(Bg + kt,                  Bs + (b ^ 1) * 2048 + w * 512);
        }
        const f16* Ab = As + b * 4096;
        const f16* Bb = Bs + b * 2048;
        f16x8 af[2], bfr[4];
#pragma unroll
        for (int mi = 0; mi < 2; mi++)
            af[mi] = *(const f16x8*)(Ab + (w * 32 + mi * 16 + l15) * 32 + quad * 8);
#pragma unroll
        for (int ni = 0; ni < 4; ni++)
            bfr[ni] = *(const f16x8*)(Bb + (ni * 16 + l15) * 32 + quad * 8);
#pragma unroll
        for (int mi = 0; mi < 2; mi++)
#pragma unroll
            for (int ni = 0; ni < 4; ni++)
                acc[mi][ni] = mfma_16x16x32(af[mi], bfr[ni], acc[mi][ni]);
        __syncthreads();
        b ^= 1;
    }

    int rb = m0 + w * 32 + quad * 4;
    if (MODE == 0) {
        if (n0 < (NH + NKV) * HD) {
            // ---- Q or K head: RoPE fused. d = ni*16+l15 (ni<2), partner ni+2.
            bool isQ = n0 < NH * HD;
            f16* dst = isQ ? (Q + ((size_t)(n0 >> 6) * SEQ) * HD)
                           : (Kk + ((size_t)((n0 - NH * HD) >> 6) * SEQ) * HD);
            float scale = isQ ? 0.18033688011112042f : 1.0f;  // (1/8)*log2(e)
            float fr[2];
#pragma unroll
            for (int ni = 0; ni < 2; ni++)
                fr[ni] = __builtin_amdgcn_exp2f(
                    (float)(ni * 16 + l15) * -0.41524101186092029f); // -log2(1e4)/32
#pragma unroll
            for (int mi = 0; mi < 2; mi++)
#pragma unroll
                for (int r = 0; r < 4; r++) {
                    int row = rb + mi * 16 + r;
                    float pv = (float)pos[row];
#pragma unroll
                    for (int ni = 0; ni < 2; ni++) {
                        float sn, cs;
                        sincosf(pv * fr[ni], &sn, &cs);
                        float x1 = acc[mi][ni][r], x2 = acc[mi][ni + 2][r];
                        int d = ni * 16 + l15;
                        dst[(size_t)row * HD + d]      = (f16)(scale * (x1 * cs - x2 * sn));
                        dst[(size_t)row * HD + d + 32] = (f16)(scale * (x2 * cs + x1 * sn));
                    }
                }
        } else {
            // ---- V^T passthrough: VT[c2][s], 4 rows contiguous in s.
#pragma unroll
            for (int mi = 0; mi < 2; mi++)
#pragma unroll
                for (int ni = 0; ni < 4; ni++) {
                    int c2 = n0 - (NH + NKV) * HD + ni * 16 + l15;
                    f16x4 v4 = { (f16)acc[mi][ni][0], (f16)acc[mi][ni][1],
                                 (f16)acc[mi][ni][2], (f16)acc[mi][ni][3] };
                    *(f16x4*)(VT + (size_t)c2 * SEQ + rb + mi * 16) = v4;
                }
        }
    } else {
#pragma unroll
        for (int mi = 0; mi < 2; mi++)
#pragma unroll
            for (int ni = 0; ni < 4; ni++)
#pragma unroll
                for (int r = 0; r < 4; r++)
                    Cf[(size_t)(rb + mi * 16 + r) * N + n0 + ni * 16 + l15] =
                        acc[mi][ni][r];
    }
}

// ---------------- fused flash attention, LDS-staged, double-buffered ----------------
// grid (SEQ/64, NH) = 1024 blocks, 4 waves; each wave owns 16 q-rows.
// K(64x64), V^T(64x64) staged per block via async16 (XOR-swizzled k-chunks),
// shared by 4 waves; ONE barrier per tile. P tile stride 72 (conflict-free b128).
__global__ __launch_bounds__(256)
void attn_fused(const f16* __restrict__ Qb, const f16* __restrict__ Kb,
                const f16* __restrict__ VTb, const float* __restrict__ mask,
                f16* __restrict__ ctx) {
    __shared__ f16 Ks[2][64 * 64];
    __shared__ f16 Vs[2][64 * 64];
    __shared__ f16 Ps[4][16 * 72];

    int t = threadIdx.x, w = t >> 6, lane = t & 63, quad = lane >> 4, l15 = lane & 15;
    int h = blockIdx.y, kvh = h >> 2;
    int qbase = blockIdx.x * 64 + w * 16;
    const f16* Qh = Qb  + (size_t)h   * SEQ * HD;
    const f16* Kh = Kb  + (size_t)kvh * SEQ * HD;
    const f16* Vh = VTb + (size_t)kvh * HD * SEQ;
    int sw = l15 & 7;
    f16* Pw = Ps[w];
    const float LOG2E = 1.4426950408889634f;

    // staging lane geometry: 8 rows x 8 chunks per async16, XOR-swizzled
    int r8 = lane >> 3;
    int cc = (lane & 7) ^ r8;
    const f16* kg0 = Kh + (size_t)(w * 16 + r8) * HD + cc * 8;
    const f16* kg1 = kg0 + 8 * HD;
    const f16* vg0 = Vh + (size_t)(w * 16 + r8) * SEQ + cc * 8;
    const f16* vg1 = vg0 + 8 * SEQ;
    int lr0 = (w * 16) * 64, lr1 = (w * 16 + 8) * 64;

    async16(kg0, &Ks[0][lr0]);
    async16(kg1, &Ks[0][lr1]);
    async16(vg0, &Vs[0][lr0]);
    async16(vg1, &Vs[0][lr1]);

    f16x8 bq[2];
#pragma unroll
    for (int ks = 0; ks < 2; ks++)
        bq[ks] = *(const f16x8*)(Qh + (size_t)(qbase + l15) * HD + ks * 32 + quad * 8);

    f32x4 o[4] = {};
    float l_part = 0.f;

    __syncthreads();
    int b = 0;

    for (int kt = 0; kt < SEQ / 64; kt++) {
        if (kt + 1 < SEQ / 64) {
            kg0 += 64 * HD; kg1 += 64 * HD; vg0 += 64; vg1 += 64;
            async16(kg0, &Ks[b ^ 1][lr0]);
            async16(kg1, &Ks[b ^ 1][lr1]);
            async16(vg0, &Vs[b ^ 1][lr0]);
            async16(vg1, &Vs[b ^ 1][lr1]);
        }
        const f16* Kb_ = &Ks[b][0];
        const f16* Vb_ = &Vs[b][0];

        // ---- S^T = K @ Q^T : rows=keys, cols=q ----
        f32x4 st[4] = {};
#pragma unroll
        for (int ni = 0; ni < 4; ni++) {
            const f16* kr = Kb_ + (ni * 16 + l15) * 64;
            f16x8 ak0 = *(const f16x8*)(kr + (quad ^ sw) * 8);
            f16x8 ak1 = *(const f16x8*)(kr + ((4 | quad) ^ sw) * 8);
            st[ni] = mfma_16x16x32(ak0, bq[0], st[ni]);
            st[ni] = mfma_16x16x32(ak1, bq[1], st[ni]);
        }
        // ---- exp2 (+mask), pack P in A-layout ----
#pragma unroll
        for (int ni = 0; ni < 4; ni++) {
            float4 m4 = *(const float4*)(mask + kt * 64 + ni * 16 + quad * 4);
            f16x4 pk;
#pragma unroll
            for (int r = 0; r < 4; r++) {
                float p = __builtin_amdgcn_exp2f(fmaf((&m4.x)[r], LOG2E, st[ni][r]));
                l_part += p;
                pk[r] = (f16)p;
            }
            *(f16x4*)(Pw + l15 * 72 + ni * 16 + quad * 4) = pk;
        }
        // ---- O += P @ V ----
        f16x8 pa0 = *(const f16x8*)(Pw + l15 * 72 + quad * 8);
        f16x8 pa1 = *(const f16x8*)(Pw + l15 * 72 + 32 + quad * 8);
#pragma unroll
        for (int dn = 0; dn < 4; dn++) {
            const f16* vr = Vb_ + (dn * 16 + l15) * 64;
            f16x8 bv0 = *(const f16x8*)(vr + (quad ^ sw) * 8);
            f16x8 bv1 = *(const f16x8*)(vr + ((4 | quad) ^ sw) * 8);
            o[dn] = mfma_16x16x32(pa0, bv0, o[dn]);
            o[dn] = mfma_16x16x32(pa1, bv1, o[dn]);
        }
        __syncthreads();
        b ^= 1;
    }

    // ---- l reduction (lane covers q = l15 over its quad's keys) ----
    float lf = l_part;
    lf += __shfl_xor(lf, 16);
    lf += __shfl_xor(lf, 32);

#pragma unroll
    for (int dn = 0; dn < 4; dn++)
#pragma unroll
        for (int r = 0; r < 4; r++) {
            int rl = quad * 4 + r;
            float lv = __shfl(lf, rl);
            int row = qbase + rl;
            ctx[(size_t)row * (NH * HD) + h * 64 + dn * 16 + l15] =
                (f16)(o[dn][r] / lv);
        }
}

// ---------------- launch ----------------
extern "C" void kernel_launch(void* const* d_in, const int* in_sizes, int n_in,
                              void* d_out, int out_size, void* d_ws, size_t ws_size,
                              hipStream_t stream) {
    const float* x    = (const float*)d_in[0];
    const float* mask = (const float*)d_in[1];
    const int*   pos  = (const int*)  d_in[2];
    const float* wq   = (const float*)d_in[3];
    const float* wk   = (const float*)d_in[4];
    const float* wv   = (const float*)d_in[5];
    const float* wo   = (const float*)d_in[6];
    float* out = (float*)d_out;

    char* ws = (char*)d_ws;
    f16* xb   = (f16*)(ws);                          // [2048][2048]   8 MB
    f16* ctx  = (f16*)(ws);                          // alias (xb dead after proj)
    f16* Wcat = (f16*)(ws + ((size_t)8  << 20));     // [3072][2048]  12 MB
    f16* woT  = (f16*)(ws + ((size_t)20 << 20));     // [2048][2048]   8 MB
    f16* Qb   = (f16*)(ws + ((size_t)28 << 20));     // [32][2048][64] 8 MB
    f16* Kb   = (f16*)(ws + ((size_t)36 << 20));     // [8][2048][64]  2 MB
    f16* VTb  = (f16*)(ws + ((size_t)38 << 20));     // [8][64][2048]  2 MB

    cvt_f32_to_f16<<<HID * SEQ / 1024, 256, 0, stream>>>(x, xb);
    transpose_all<<<dim3(64, 64, 4), dim3(32, 8), 0, stream>>>(
        wq, wk, wv, wo, Wcat, woT);

    // fused Q/K/V projection + RoPE epilogue: C[2048,3072] = xb @ Wcat^T
    gemm_bt<0><<<dim3(3072 / 64, 2048 / 128), 256, 0, stream>>>(
        xb, Wcat, nullptr, Qb, Kb, VTb, pos, 3072, 2048);

    attn_fused<<<dim3(SEQ / 64, NH), 256, 0, stream>>>(Qb, Kb, VTb, mask, ctx);

    // out = ctx @ wo  (fp32 output)
    gemm_bt<2><<<dim3(2048 / 64, 2048 / 128), 256, 0, stream>>>(
        ctx, woT, out, nullptr, nullptr, nullptr, nullptr, 2048, 2048);
}

// Round 6
// 263.631 us; speedup vs baseline: 1.0660x; 1.0660x over previous
//
#include <hip/hip_runtime.h>

#define SEQ 2048
#define HID 2048
#define NH  32
#define NKV 8
#define HD  64

typedef _Float16 f16;
typedef __attribute__((ext_vector_type(4))) _Float16 f16x4;
typedef __attribute__((ext_vector_type(8))) _Float16 f16x8;
typedef __attribute__((ext_vector_type(4))) float    f32x4;

__device__ __forceinline__ f32x4 mfma_16x16x32(f16x8 a, f16x8 b, f32x4 c) {
    return __builtin_amdgcn_mfma_f32_16x16x32_f16(a, b, c, 0, 0, 0);
}

// async global->LDS, 16B per lane. Global address is PER-LANE (gather);
// LDS dest is wave-uniform base + lane*16 (contiguous).
__device__ __forceinline__ void async16(const void* g, void* l) {
    __builtin_amdgcn_global_load_lds(
        (const __attribute__((address_space(1))) void*)g,
        (__attribute__((address_space(3))) void*)l,
        16, 0, 0);
}

// ---------------- prep kernels ----------------

__global__ void cvt_f32_to_f16(const float* __restrict__ src, f16* __restrict__ dst) {
    int i = (blockIdx.x * 256 + threadIdx.x) * 4;
    float4 v = *(const float4*)(src + i);
    f16x4 o = { (f16)v.x, (f16)v.y, (f16)v.z, (f16)v.w };
    *(f16x4*)(dst + i) = o;
}

// All four weight transposes in one launch; route by blockIdx.z.
// dst[c][r] = (f16)src[r][c];  R = 2048 rows for all.
__global__ void transpose_all(const float* __restrict__ wq, const float* __restrict__ wk,
                              const float* __restrict__ wv, const float* __restrict__ wo,
                              f16* __restrict__ Wcat, f16* __restrict__ woT) {
    __shared__ float tile[32][33];
    int z = blockIdx.z;
    const float* src; f16* dst; int C;
    if      (z == 0) { src = wq; dst = Wcat;                         C = 2048; }
    else if (z == 1) { src = wk; dst = Wcat + (size_t)2048 * 2048;   C = 512;  }
    else if (z == 2) { src = wv; dst = Wcat + (size_t)2560 * 2048;   C = 512;  }
    else             { src = wo; dst = woT;                          C = 2048; }
    int c0 = blockIdx.x * 32, r0 = blockIdx.y * 32;
    if (c0 >= C) return;
    int tx = threadIdx.x, ty = threadIdx.y;
#pragma unroll
    for (int i = 0; i < 32; i += 8)
        tile[ty + i][tx] = src[(size_t)(r0 + ty + i) * C + c0 + tx];
    __syncthreads();
#pragma unroll
    for (int i = 0; i < 32; i += 8)
        dst[(size_t)(c0 + ty + i) * 2048 + r0 + tx] = (f16)tile[tx][ty + i];
}

// ---------------- GEMM: C[M,N] = A[M,K] @ BT[N,K]^T ----------------
// 128(M) x 64(N) tile, BK=32, 4 waves as 4x1 (wave w: rows w*32..+31, all 64 n).
// Single-barrier double-buffered LDS staging (prefetch in flight during compute).
// MODE 0: fused QKV epilogue with RoPE: n0<2048 -> Q (RoPE, scaled 1/8*log2e);
//         n0<2560 -> K (RoPE); else -> V^T passthrough (f16x4 stores).
// MODE 2: fp32 row-major into Cf.
template <int MODE>
__global__ __launch_bounds__(256)
void gemm_bt(const f16* __restrict__ A, const f16* __restrict__ BT,
             float* __restrict__ Cf, f16* __restrict__ Q, f16* __restrict__ Kk,
             f16* __restrict__ VT, const int* __restrict__ pos, int N, int K) {
    __shared__ f16 As[2 * 128 * 32];
    __shared__ f16 Bs[2 * 64 * 32];
    int t = threadIdx.x;
    int w = t >> 6, lane = t & 63, quad = lane >> 4, l15 = lane & 15;
    int m0 = blockIdx.y * 128, n0 = blockIdx.x * 64;

    int srow  = t >> 2;        // 0..63
    int skoff = (t & 3) * 8;
    const f16* Ag = A  + (size_t)(m0 + srow) * K + skoff;
    const f16* Bg = BT + (size_t)(n0 + srow) * K + skoff;

    f32x4 acc[2][4] = {};

    // stage tile 0
    async16(Ag,                  As + w * 512);
    async16(Ag + (size_t)64 * K, As + 2048 + w * 512);
    async16(Bg,                  Bs + w * 512);
    __syncthreads();

    int b = 0;
    for (int kt = 32; kt <= K; kt += 32) {
        if (kt < K) {   // prefetch next tile into buf b^1
            async16(Ag + kt,                  As + (b ^ 1) * 4096 + w * 512);
            async16(Ag + (size_t)64 * K + kt, As + (b ^ 1) * 4096 + 2048 + w * 512);
            async16(Bg + kt,                  Bs + (b ^ 1) * 2048 + w * 512);
        }
        const f16* Ab = As + b * 4096;
        const f16* Bb = Bs + b * 2048;
        f16x8 af[2], bfr[4];
#pragma unroll
        for (int mi = 0; mi < 2; mi++)
            af[mi] = *(const f16x8*)(Ab + (w * 32 + mi * 16 + l15) * 32 + quad * 8);
#pragma unroll
        for (int ni = 0; ni < 4; ni++)
            bfr[ni] = *(const f16x8*)(Bb + (ni * 16 + l15) * 32 + quad * 8);
#pragma unroll
        for (int mi = 0; mi < 2; mi++)
#pragma unroll
            for (int ni = 0; ni < 4; ni++)
                acc[mi][ni] = mfma_16x16x32(af[mi], bfr[ni], acc[mi][ni]);
        __syncthreads();
        b ^= 1;
    }

    int rb = m0 + w * 32 + quad * 4;
    if (MODE == 0) {
        if (n0 < (NH + NKV) * HD) {
            // ---- Q or K head: RoPE fused. d = ni*16+l15 (ni<2), partner ni+2.
            bool isQ = n0 < NH * HD;
            f16* dst = isQ ? (Q + ((size_t)(n0 >> 6) * SEQ) * HD)
                           : (Kk + ((size_t)((n0 - NH * HD) >> 6) * SEQ) * HD);
            float scale = isQ ? 0.18033688011112042f : 1.0f;  // (1/8)*log2(e)
            float fr[2];
#pragma unroll
            for (int ni = 0; ni < 2; ni++)
                fr[ni] = __builtin_amdgcn_exp2f(
                    (float)(ni * 16 + l15) * -0.41524101186092029f); // -log2(1e4)/32
#pragma unroll
            for (int mi = 0; mi < 2; mi++)
#pragma unroll
                for (int r = 0; r < 4; r++) {
                    int row = rb + mi * 16 + r;
                    float pv = (float)pos[row];
#pragma unroll
                    for (int ni = 0; ni < 2; ni++) {
                        float sn, cs;
                        sincosf(pv * fr[ni], &sn, &cs);
                        float x1 = acc[mi][ni][r], x2 = acc[mi][ni + 2][r];
                        int d = ni * 16 + l15;
                        dst[(size_t)row * HD + d]      = (f16)(scale * (x1 * cs - x2 * sn));
                        dst[(size_t)row * HD + d + 32] = (f16)(scale * (x2 * cs + x1 * sn));
                    }
                }
        } else {
            // ---- V^T passthrough: VT[c2][s], 4 rows contiguous in s.
#pragma unroll
            for (int mi = 0; mi < 2; mi++)
#pragma unroll
                for (int ni = 0; ni < 4; ni++) {
                    int c2 = n0 - (NH + NKV) * HD + ni * 16 + l15;
                    f16x4 v4 = { (f16)acc[mi][ni][0], (f16)acc[mi][ni][1],
                                 (f16)acc[mi][ni][2], (f16)acc[mi][ni][3] };
                    *(f16x4*)(VT + (size_t)c2 * SEQ + rb + mi * 16) = v4;
                }
        }
    } else {
#pragma unroll
        for (int mi = 0; mi < 2; mi++)
#pragma unroll
            for (int ni = 0; ni < 4; ni++)
#pragma unroll
                for (int r = 0; r < 4; r++)
                    Cf[(size_t)(rb + mi * 16 + r) * N + n0 + ni * 16 + l15] =
                        acc[mi][ni][r];
    }
}

// ---------------- fused flash attention, LDS-staged, double-buffered ----------------
// grid (SEQ/128, NH) = 512 blocks, 4 waves; each wave owns 32 q-rows.
// K(64x64), V^T(64x64) staged per block via async16 (XOR-swizzled k-chunks),
// shared by 4 waves; ONE barrier per tile. P stride 72; mask read direct from
// global (L1-broadcast). LDS = 50 KB -> 3 blocks/CU.
__global__ __launch_bounds__(256)
void attn_fused(const f16* __restrict__ Qb, const f16* __restrict__ Kb,
                const f16* __restrict__ VTb, const float* __restrict__ mask,
                f16* __restrict__ ctx) {
    __shared__ f16 Ks[2][64 * 64];
    __shared__ f16 Vs[2][64 * 64];
    __shared__ f16 Ps[4][32 * 72];

    int t = threadIdx.x, w = t >> 6, lane = t & 63, quad = lane >> 4, l15 = lane & 15;
    int h = blockIdx.y, kvh = h >> 2;
    int qbase = blockIdx.x * 128 + w * 32;
    const f16* Qh = Qb  + (size_t)h   * SEQ * HD;
    const f16* Kh = Kb  + (size_t)kvh * SEQ * HD;
    const f16* Vh = VTb + (size_t)kvh * HD * SEQ;
    int sw = l15 & 7;
    f16* Pw = Ps[w];
    const float LOG2E = 1.4426950408889634f;

    // staging lane geometry: 8 rows x 8 chunks per async16, XOR-swizzled
    int r8 = lane >> 3;
    int cc = (lane & 7) ^ r8;
    const f16* kg0 = Kh + (size_t)(w * 16 + r8) * HD + cc * 8;
    const f16* kg1 = kg0 + 8 * HD;
    const f16* vg0 = Vh + (size_t)(w * 16 + r8) * SEQ + cc * 8;
    const f16* vg1 = vg0 + 8 * SEQ;
    int lr0 = (w * 16) * 64, lr1 = (w * 16 + 8) * 64;

    async16(kg0, &Ks[0][lr0]);
    async16(kg1, &Ks[0][lr1]);
    async16(vg0, &Vs[0][lr0]);
    async16(vg1, &Vs[0][lr1]);

    // ---- Q fragments (persistent): B-operand, n = q ----
    f16x8 bq[2][2];
#pragma unroll
    for (int qg = 0; qg < 2; qg++)
#pragma unroll
        for (int ks = 0; ks < 2; ks++)
            bq[qg][ks] = *(const f16x8*)(Qh + (size_t)(qbase + qg * 16 + l15) * HD
                                            + ks * 32 + quad * 8);

    f32x4 o[2][4] = {};
    float l_part[2] = {0.f, 0.f};

    __syncthreads();
    int b = 0;

    for (int kt = 0; kt < SEQ / 64; kt++) {
        if (kt + 1 < SEQ / 64) {
            kg0 += 64 * HD; kg1 += 64 * HD; vg0 += 64; vg1 += 64;
            async16(kg0, &Ks[b ^ 1][lr0]);
            async16(kg1, &Ks[b ^ 1][lr1]);
            async16(vg0, &Vs[b ^ 1][lr0]);
            async16(vg1, &Vs[b ^ 1][lr1]);
        }
        const f16* Kb_ = &Ks[b][0];
        const f16* Vb_ = &Vs[b][0];

        // ---- S^T = K @ Q^T : rows=keys, cols=q ----
        f32x4 st[4][2] = {};
#pragma unroll
        for (int ni = 0; ni < 4; ni++) {
            const f16* kr = Kb_ + (ni * 16 + l15) * 64;
            f16x8 ak0 = *(const f16x8*)(kr + (quad ^ sw) * 8);
            f16x8 ak1 = *(const f16x8*)(kr + ((4 | quad) ^ sw) * 8);
#pragma unroll
            for (int qg = 0; qg < 2; qg++) {
                st[ni][qg] = mfma_16x16x32(ak0, bq[qg][0], st[ni][qg]);
                st[ni][qg] = mfma_16x16x32(ak1, bq[qg][1], st[ni][qg]);
            }
        }
        // ---- exp2 (+mask, pre-scaled by log2e), pack P in A-layout ----
#pragma unroll
        for (int ni = 0; ni < 4; ni++) {
            float4 m4 = *(const float4*)(mask + kt * 64 + ni * 16 + quad * 4);
#pragma unroll
            for (int qg = 0; qg < 2; qg++) {
                f16x4 pk;
#pragma unroll
                for (int r = 0; r < 4; r++) {
                    float p = __builtin_amdgcn_exp2f(
                        fmaf((&m4.x)[r], LOG2E, st[ni][qg][r]));
                    l_part[qg] += p;
                    pk[r] = (f16)p;
                }
                *(f16x4*)(Pw + (qg * 16 + l15) * 72 + ni * 16 + quad * 4) = pk;
            }
        }
        // ---- O += P @ V ----
        f16x8 pa[2][2];
#pragma unroll
        for (int mi = 0; mi < 2; mi++)
#pragma unroll
            for (int ks = 0; ks < 2; ks++)
                pa[mi][ks] = *(const f16x8*)(Pw + (mi * 16 + l15) * 72
                                                + ks * 32 + quad * 8);
#pragma unroll
        for (int dn = 0; dn < 4; dn++) {
            const f16* vr = Vb_ + (dn * 16 + l15) * 64;
            f16x8 bv0 = *(const f16x8*)(vr + (quad ^ sw) * 8);
            f16x8 bv1 = *(const f16x8*)(vr + ((4 | quad) ^ sw) * 8);
#pragma unroll
            for (int mi = 0; mi < 2; mi++) {
                o[mi][dn] = mfma_16x16x32(pa[mi][0], bv0, o[mi][dn]);
                o[mi][dn] = mfma_16x16x32(pa[mi][1], bv1, o[mi][dn]);
            }
        }
        __syncthreads();
        b ^= 1;
    }

    // ---- l reduction: lane's l_part[qg] covers q = qg*16+l15 over its quad keys ----
    float linv[2];
#pragma unroll
    for (int qg = 0; qg < 2; qg++) {
        float lf = l_part[qg];
        lf += __shfl_xor(lf, 16);
        lf += __shfl_xor(lf, 32);
        linv[qg] = lf;
    }
#pragma unroll
    for (int mi = 0; mi < 2; mi++)
#pragma unroll
        for (int dn = 0; dn < 4; dn++)
#pragma unroll
            for (int r = 0; r < 4; r++) {
                int rl = quad * 4 + r;
                float lv = __shfl(linv[mi], rl);
                int row = qbase + mi * 16 + rl;
                ctx[(size_t)row * (NH * HD) + h * 64 + dn * 16 + l15] =
                    (f16)(o[mi][dn][r] / lv);
            }
}

// ---------------- launch ----------------
extern "C" void kernel_launch(void* const* d_in, const int* in_sizes, int n_in,
                              void* d_out, int out_size, void* d_ws, size_t ws_size,
                              hipStream_t stream) {
    const float* x    = (const float*)d_in[0];
    const float* mask = (const float*)d_in[1];
    const int*   pos  = (const int*)  d_in[2];
    const float* wq   = (const float*)d_in[3];
    const float* wk   = (const float*)d_in[4];
    const float* wv   = (const float*)d_in[5];
    const float* wo   = (const float*)d_in[6];
    float* out = (float*)d_out;

    char* ws = (char*)d_ws;
    f16* xb   = (f16*)(ws);                          // [2048][2048]   8 MB
    f16* ctx  = (f16*)(ws);                          // alias (xb dead after proj)
    f16* Wcat = (f16*)(ws + ((size_t)8  << 20));     // [3072][2048]  12 MB
    f16* woT  = (f16*)(ws + ((size_t)20 << 20));     // [2048][2048]   8 MB
    f16* Qb   = (f16*)(ws + ((size_t)28 << 20));     // [32][2048][64] 8 MB
    f16* Kb   = (f16*)(ws + ((size_t)36 << 20));     // [8][2048][64]  2 MB
    f16* VTb  = (f16*)(ws + ((size_t)38 << 20));     // [8][64][2048]  2 MB

    cvt_f32_to_f16<<<HID * SEQ / 1024, 256, 0, stream>>>(x, xb);
    transpose_all<<<dim3(64, 64, 4), dim3(32, 8), 0, stream>>>(
        wq, wk, wv, wo, Wcat, woT);

    // fused Q/K/V projection + RoPE epilogue: C[2048,3072] = xb @ Wcat^T
    gemm_bt<0><<<dim3(3072 / 64, 2048 / 128), 256, 0, stream>>>(
        xb, Wcat, nullptr, Qb, Kb, VTb, pos, 3072, 2048);

    attn_fused<<<dim3(SEQ / 128, NH), 256, 0, stream>>>(Qb, Kb, VTb, mask, ctx);

    // out = ctx @ wo  (fp32 output)
    gemm_bt<2><<<dim3(2048 / 64, 2048 / 128), 256, 0, stream>>>(
        ctx, woT, out, nullptr, nullptr, nullptr, nullptr, 2048, 2048);
}

// Round 7
// 260.971 us; speedup vs baseline: 1.0769x; 1.0102x over previous
//
#include <hip/hip_runtime.h>

#define SEQ 2048
#define HID 2048
#define NH  32
#define NKV 8
#define HD  64

typedef _Float16 f16;
typedef __attribute__((ext_vector_type(4))) _Float16 f16x4;
typedef __attribute__((ext_vector_type(8))) _Float16 f16x8;
typedef __attribute__((ext_vector_type(4))) float    f32x4;

__device__ __forceinline__ f32x4 mfma_16x16x32(f16x8 a, f16x8 b, f32x4 c) {
    return __builtin_amdgcn_mfma_f32_16x16x32_f16(a, b, c, 0, 0, 0);
}

// async global->LDS, 16B per lane. Global address is PER-LANE (gather);
// LDS dest is wave-uniform base + lane*16 (contiguous).
__device__ __forceinline__ void async16(const void* g, void* l) {
    __builtin_amdgcn_global_load_lds(
        (const __attribute__((address_space(1))) void*)g,
        (__attribute__((address_space(3))) void*)l,
        16, 0, 0);
}

// ---------------- prep kernels ----------------

__global__ void cvt_f32_to_f16(const float* __restrict__ src, f16* __restrict__ dst) {
    int i = (blockIdx.x * 256 + threadIdx.x) * 4;
    float4 v = *(const float4*)(src + i);
    f16x4 o = { (f16)v.x, (f16)v.y, (f16)v.z, (f16)v.w };
    *(f16x4*)(dst + i) = o;
}

// All four weight transposes in one launch; route by blockIdx.z.
__global__ void transpose_all(const float* __restrict__ wq, const float* __restrict__ wk,
                              const float* __restrict__ wv, const float* __restrict__ wo,
                              f16* __restrict__ Wcat, f16* __restrict__ woT) {
    __shared__ float tile[32][33];
    int z = blockIdx.z;
    const float* src; f16* dst; int C;
    if      (z == 0) { src = wq; dst = Wcat;                         C = 2048; }
    else if (z == 1) { src = wk; dst = Wcat + (size_t)2048 * 2048;   C = 512;  }
    else if (z == 2) { src = wv; dst = Wcat + (size_t)2560 * 2048;   C = 512;  }
    else             { src = wo; dst = woT;                          C = 2048; }
    int c0 = blockIdx.x * 32, r0 = blockIdx.y * 32;
    if (c0 >= C) return;
    int tx = threadIdx.x, ty = threadIdx.y;
#pragma unroll
    for (int i = 0; i < 32; i += 8)
        tile[ty + i][tx] = src[(size_t)(r0 + ty + i) * C + c0 + tx];
    __syncthreads();
#pragma unroll
    for (int i = 0; i < 32; i += 8)
        dst[(size_t)(c0 + ty + i) * 2048 + r0 + tx] = (f16)tile[tx][ty + i];
}

// ---------------- GEMM: C[M,N] = A[M,K] @ BT[N,K]^T ----------------
// 128x128 tile (m97 AI), BK=32, 4 waves 2x2, single-barrier dbuf staging.
// blockIdx.z = K-split index (A/BT advanced by z*Klen; MODE 1 writes partial z).
// MODE 0: fused QKV epilogue + RoPE (head = 64-aligned wave column, uniform).
// MODE 1: f16 row-major partial into Cp + z*2048*2048.
template <int MODE>
__global__ __launch_bounds__(256)
void gemm_bt(const f16* __restrict__ A, const f16* __restrict__ BT,
             f16* __restrict__ Cp, f16* __restrict__ Q, f16* __restrict__ Kk,
             f16* __restrict__ VT, const int* __restrict__ pos,
             int N, int Kstride, int Klen) {
    __shared__ f16 As[2][128 * 32];
    __shared__ f16 Bs[2][128 * 32];
    int t = threadIdx.x;
    int w = t >> 6, lane = t & 63, quad = lane >> 4, l15 = lane & 15;
    int wm = w >> 1, wn = w & 1;
    int m0 = blockIdx.y * 128, n0 = blockIdx.x * 128;
    size_t koff = (size_t)blockIdx.z * Klen;

    int srow  = t >> 2;        // 0..63
    int skoff = (t & 3) * 8;
    const f16* Ag = A  + (size_t)(m0 + srow) * Kstride + koff + skoff;
    const f16* Bg = BT + (size_t)(n0 + srow) * Kstride + koff + skoff;

    f32x4 acc[4][4] = {};

    // stage tile 0
    async16(Ag,                        &As[0][w * 512]);
    async16(Ag + (size_t)64 * Kstride, &As[0][2048 + w * 512]);
    async16(Bg,                        &Bs[0][w * 512]);
    async16(Bg + (size_t)64 * Kstride, &Bs[0][2048 + w * 512]);
    __syncthreads();

    int b = 0;
    for (int kt = 32; kt <= Klen; kt += 32) {
        if (kt < Klen) {
            async16(Ag + kt,                        &As[b ^ 1][w * 512]);
            async16(Ag + (size_t)64 * Kstride + kt, &As[b ^ 1][2048 + w * 512]);
            async16(Bg + kt,                        &Bs[b ^ 1][w * 512]);
            async16(Bg + (size_t)64 * Kstride + kt, &Bs[b ^ 1][2048 + w * 512]);
        }
        f16x8 af[4], bf[4];
#pragma unroll
        for (int mi = 0; mi < 4; mi++)
            af[mi] = *(const f16x8*)(&As[b][(wm * 64 + mi * 16 + l15) * 32 + quad * 8]);
#pragma unroll
        for (int ni = 0; ni < 4; ni++)
            bf[ni] = *(const f16x8*)(&Bs[b][(wn * 64 + ni * 16 + l15) * 32 + quad * 8]);
#pragma unroll
        for (int mi = 0; mi < 4; mi++)
#pragma unroll
            for (int ni = 0; ni < 4; ni++)
                acc[mi][ni] = mfma_16x16x32(af[mi], bf[ni], acc[mi][ni]);
        __syncthreads();
        b ^= 1;
    }

    int rb  = m0 + wm * 64 + quad * 4;
    int cbh = n0 + wn * 64;          // 64-aligned: one head per wave column
    if (MODE == 0) {
        if (cbh < (NH + NKV) * HD) {
            // ---- Q or K head: RoPE fused. d = ni*16+l15 (ni<2), partner ni+2.
            bool isQ = cbh < NH * HD;
            f16* dst = isQ ? (Q  + (size_t)(cbh >> 6) * SEQ * HD)
                           : (Kk + (size_t)((cbh - NH * HD) >> 6) * SEQ * HD);
            float scale = isQ ? 0.18033688011112042f : 1.0f;  // (1/8)*log2(e)
            float fr[2];
#pragma unroll
            for (int ni = 0; ni < 2; ni++)
                fr[ni] = __builtin_amdgcn_exp2f(
                    (float)(ni * 16 + l15) * -0.41524101186092029f); // -log2(1e4)/32
#pragma unroll
            for (int mi = 0; mi < 4; mi++)
#pragma unroll
                for (int r = 0; r < 4; r++) {
                    int row = rb + mi * 16 + r;
                    float pv = (float)pos[row];
#pragma unroll
                    for (int ni = 0; ni < 2; ni++) {
                        float sn, cs;
                        __sincosf(pv * fr[ni], &sn, &cs);
                        float x1 = acc[mi][ni][r], x2 = acc[mi][ni + 2][r];
                        int d = ni * 16 + l15;
                        dst[(size_t)row * HD + d]      = (f16)(scale * (x1 * cs - x2 * sn));
                        dst[(size_t)row * HD + d + 32] = (f16)(scale * (x2 * cs + x1 * sn));
                    }
                }
        } else {
            // ---- V^T passthrough: VT[c2][s], 4 rows contiguous in s.
#pragma unroll
            for (int mi = 0; mi < 4; mi++)
#pragma unroll
                for (int ni = 0; ni < 4; ni++) {
                    int c2 = cbh - (NH + NKV) * HD + ni * 16 + l15;
                    f16x4 v4 = { (f16)acc[mi][ni][0], (f16)acc[mi][ni][1],
                                 (f16)acc[mi][ni][2], (f16)acc[mi][ni][3] };
                    *(f16x4*)(VT + (size_t)c2 * SEQ + rb + mi * 16) = v4;
                }
        }
    } else {
        f16* Co = Cp + (size_t)blockIdx.z * 2048 * 2048;
#pragma unroll
        for (int mi = 0; mi < 4; mi++)
#pragma unroll
            for (int ni = 0; ni < 4; ni++)
#pragma unroll
                for (int r = 0; r < 4; r++)
                    Co[(size_t)(rb + mi * 16 + r) * N + cbh + ni * 16 + l15] =
                        (f16)acc[mi][ni][r];
    }
}

// ---------------- fused flash attention, split-K over key tiles ----------------
// grid (SEQ/128, NH, 2), block 256 = 4 waves; wave owns 32 q-rows; split z owns
// 16 of 32 key tiles. K/V staged per block (XOR-swizzled), dbuf, ONE barrier.
// Writes unnormalized O (f16) + l (f32) partials; combine kernel normalizes.
__global__ __launch_bounds__(256)
void attn_fused(const f16* __restrict__ Qb, const f16* __restrict__ Kb,
                const f16* __restrict__ VTb, const float* __restrict__ mask,
                f16* __restrict__ Opart, float* __restrict__ Lpart) {
    __shared__ f16 Ks[2][64 * 64];
    __shared__ f16 Vs[2][64 * 64];
    __shared__ f16 Ps[4][32 * 72];

    int t = threadIdx.x, w = t >> 6, lane = t & 63, quad = lane >> 4, l15 = lane & 15;
    int h = blockIdx.y, kvh = h >> 2, split = blockIdx.z;
    int qbase = blockIdx.x * 128 + w * 32;
    int key0  = split * (SEQ / 2);
    const f16* Qh = Qb  + (size_t)h   * SEQ * HD;
    const f16* Kh = Kb  + (size_t)kvh * SEQ * HD;
    const f16* Vh = VTb + (size_t)kvh * HD * SEQ;
    int sw = l15 & 7;
    f16* Pw = Ps[w];
    const float LOG2E = 1.4426950408889634f;

    // staging lane geometry: 8 rows x 8 chunks per async16, XOR-swizzled
    int r8 = lane >> 3;
    int cc = (lane & 7) ^ r8;
    const f16* kg0 = Kh + (size_t)(key0 + w * 16 + r8) * HD + cc * 8;
    const f16* kg1 = kg0 + 8 * HD;
    const f16* vg0 = Vh + (size_t)(w * 16 + r8) * SEQ + key0 + cc * 8;
    const f16* vg1 = vg0 + 8 * SEQ;
    int lr0 = (w * 16) * 64, lr1 = (w * 16 + 8) * 64;

    async16(kg0, &Ks[0][lr0]);
    async16(kg1, &Ks[0][lr1]);
    async16(vg0, &Vs[0][lr0]);
    async16(vg1, &Vs[0][lr1]);

    // ---- Q fragments (persistent): B-operand, n = q ----
    f16x8 bq[2][2];
#pragma unroll
    for (int qg = 0; qg < 2; qg++)
#pragma unroll
        for (int ks = 0; ks < 2; ks++)
            bq[qg][ks] = *(const f16x8*)(Qh + (size_t)(qbase + qg * 16 + l15) * HD
                                            + ks * 32 + quad * 8);

    f32x4 o[2][4] = {};
    float l_part[2] = {0.f, 0.f};

    __syncthreads();
    int b = 0;

    for (int ktl = 0; ktl < SEQ / 128; ktl++) {
        if (ktl + 1 < SEQ / 128) {
            kg0 += 64 * HD; kg1 += 64 * HD; vg0 += 64; vg1 += 64;
            async16(kg0, &Ks[b ^ 1][lr0]);
            async16(kg1, &Ks[b ^ 1][lr1]);
            async16(vg0, &Vs[b ^ 1][lr0]);
            async16(vg1, &Vs[b ^ 1][lr1]);
        }
        const f16* Kb_ = &Ks[b][0];
        const f16* Vb_ = &Vs[b][0];

        // ---- S^T = K @ Q^T : rows=keys, cols=q ----
        f32x4 st[4][2] = {};
#pragma unroll
        for (int ni = 0; ni < 4; ni++) {
            const f16* kr = Kb_ + (ni * 16 + l15) * 64;
            f16x8 ak0 = *(const f16x8*)(kr + (quad ^ sw) * 8);
            f16x8 ak1 = *(const f16x8*)(kr + ((4 | quad) ^ sw) * 8);
#pragma unroll
            for (int qg = 0; qg < 2; qg++) {
                st[ni][qg] = mfma_16x16x32(ak0, bq[qg][0], st[ni][qg]);
                st[ni][qg] = mfma_16x16x32(ak1, bq[qg][1], st[ni][qg]);
            }
        }
        // ---- exp2 (+mask, scores pre-scaled by log2e), pack P in A-layout ----
#pragma unroll
        for (int ni = 0; ni < 4; ni++) {
            float4 m4 = *(const float4*)(mask + key0 + ktl * 64 + ni * 16 + quad * 4);
#pragma unroll
            for (int qg = 0; qg < 2; qg++) {
                f16x4 pk;
#pragma unroll
                for (int r = 0; r < 4; r++) {
                    float p = __builtin_amdgcn_exp2f(
                        fmaf((&m4.x)[r], LOG2E, st[ni][qg][r]));
                    l_part[qg] += p;
                    pk[r] = (f16)p;
                }
                *(f16x4*)(Pw + (qg * 16 + l15) * 72 + ni * 16 + quad * 4) = pk;
            }
        }
        // ---- O += P @ V ----
        f16x8 pa[2][2];
#pragma unroll
        for (int mi = 0; mi < 2; mi++)
#pragma unroll
            for (int ks = 0; ks < 2; ks++)
                pa[mi][ks] = *(const f16x8*)(Pw + (mi * 16 + l15) * 72
                                                + ks * 32 + quad * 8);
#pragma unroll
        for (int dn = 0; dn < 4; dn++) {
            const f16* vr = Vb_ + (dn * 16 + l15) * 64;
            f16x8 bv0 = *(const f16x8*)(vr + (quad ^ sw) * 8);
            f16x8 bv1 = *(const f16x8*)(vr + ((4 | quad) ^ sw) * 8);
#pragma unroll
            for (int mi = 0; mi < 2; mi++) {
                o[mi][dn] = mfma_16x16x32(pa[mi][0], bv0, o[mi][dn]);
                o[mi][dn] = mfma_16x16x32(pa[mi][1], bv1, o[mi][dn]);
            }
        }
        __syncthreads();
        b ^= 1;
    }

    // ---- partial l: lane's l_part[qg] covers q = qg*16+l15 over its quad keys ----
    float lf[2];
#pragma unroll
    for (int qg = 0; qg < 2; qg++) {
        float v = l_part[qg];
        v += __shfl_xor(v, 16);
        v += __shfl_xor(v, 32);
        lf[qg] = v;
    }
    if (quad == 0) {
#pragma unroll
        for (int qg = 0; qg < 2; qg++)
            Lpart[((size_t)split * NH + h) * SEQ + qbase + qg * 16 + l15] = lf[qg];
    }
    // ---- unnormalized O partial: Opart[split][h][row][d] f16 ----
    f16* Op = Opart + ((size_t)split * NH + h) * SEQ * HD;
#pragma unroll
    for (int mi = 0; mi < 2; mi++)
#pragma unroll
        for (int dn = 0; dn < 4; dn++)
#pragma unroll
            for (int r = 0; r < 4; r++) {
                int row = qbase + mi * 16 + quad * 4 + r;
                Op[(size_t)row * HD + dn * 16 + l15] = (f16)o[mi][dn][r];
            }
}

// ---------------- combine: ctx[row][h*64+d] = (O0+O1)/(l0+l1) ----------------
__global__ void attn_combine(const f16* __restrict__ O, const float* __restrict__ L,
                             f16* __restrict__ ctx) {
    int idx = blockIdx.x * 256 + threadIdx.x;   // one f16x4 per thread
    int c4  = idx & 511;
    int row = idx >> 9;
    int col = c4 * 4;
    int h   = col >> 6;
    float l = L[(size_t)h * SEQ + row] + L[(size_t)(NH + h) * SEQ + row];
    const f16* o0 = O + ((size_t)h * SEQ + row) * HD + (col & 63);
    const f16* o1 = o0 + (size_t)NH * SEQ * HD;
    f16x4 a = *(const f16x4*)o0, b = *(const f16x4*)o1;
    float inv = 1.0f / l;
    f16x4 r;
#pragma unroll
    for (int j = 0; j < 4; j++)
        r[j] = (f16)(((float)a[j] + (float)b[j]) * inv);
    *(f16x4*)(ctx + (size_t)row * (NH * HD) + col) = r;
}

// ---------------- combine: out = P0 + P1 (fp32) ----------------
__global__ void add_out(const f16* __restrict__ P0, const f16* __restrict__ P1,
                        float* __restrict__ out) {
    int i = (blockIdx.x * 256 + threadIdx.x) * 8;
    f16x8 a = *(const f16x8*)(P0 + i);
    f16x8 b = *(const f16x8*)(P1 + i);
    float4 o0, o1;
    o0.x = (float)a[0] + (float)b[0]; o0.y = (float)a[1] + (float)b[1];
    o0.z = (float)a[2] + (float)b[2]; o0.w = (float)a[3] + (float)b[3];
    o1.x = (float)a[4] + (float)b[4]; o1.y = (float)a[5] + (float)b[5];
    o1.z = (float)a[6] + (float)b[6]; o1.w = (float)a[7] + (float)b[7];
    *(float4*)(out + i)     = o0;
    *(float4*)(out + i + 4) = o1;
}

// ---------------- launch ----------------
extern "C" void kernel_launch(void* const* d_in, const int* in_sizes, int n_in,
                              void* d_out, int out_size, void* d_ws, size_t ws_size,
                              hipStream_t stream) {
    const float* x    = (const float*)d_in[0];
    const float* mask = (const float*)d_in[1];
    const int*   pos  = (const int*)  d_in[2];
    const float* wq   = (const float*)d_in[3];
    const float* wk   = (const float*)d_in[4];
    const float* wv   = (const float*)d_in[5];
    const float* wo   = (const float*)d_in[6];
    float* out = (float*)d_out;

    char* ws = (char*)d_ws;
    // phase 1-2: xb [0,8M), Wcat [8M,20M), woT [20M,28M), Qb [28M,36M),
    //            Kb [36M,38M), VTb [38M,40M)
    // phase 3-4: Opart [0,16M) (2 splits x 8M, xb/Wcat dead), Lpart [16M,16.5M),
    //            ctx [28M,36M) (Qb region, written by combine)
    // phase 5-6: Pp0 [0,8M), Pp1 [8M,16M) (Opart dead), woT/ctx still live
    f16*   xb    = (f16*)(ws);
    f16*   Wcat  = (f16*)(ws + ((size_t)8  << 20));
    f16*   woT   = (f16*)(ws + ((size_t)20 << 20));
    f16*   Qb    = (f16*)(ws + ((size_t)28 << 20));
    f16*   Kb    = (f16*)(ws + ((size_t)36 << 20));
    f16*   VTb   = (f16*)(ws + ((size_t)38 << 20));
    f16*   Opart = (f16*)(ws);
    float* Lpart = (float*)(ws + ((size_t)16 << 20));
    f16*   ctx   = (f16*)(ws + ((size_t)28 << 20));
    f16*   Pp    = (f16*)(ws);

    cvt_f32_to_f16<<<HID * SEQ / 1024, 256, 0, stream>>>(x, xb);
    transpose_all<<<dim3(64, 64, 4), dim3(32, 8), 0, stream>>>(
        wq, wk, wv, wo, Wcat, woT);

    // fused Q/K/V projection + RoPE epilogue: C[2048,3072] = xb @ Wcat^T
    gemm_bt<0><<<dim3(3072 / 128, 2048 / 128, 1), 256, 0, stream>>>(
        xb, Wcat, nullptr, Qb, Kb, VTb, pos, 3072, 2048, 2048);

    attn_fused<<<dim3(SEQ / 128, NH, 2), 256, 0, stream>>>(
        Qb, Kb, VTb, mask, Opart, Lpart);
    attn_combine<<<SEQ * NH * HD / 4 / 256, 256, 0, stream>>>(Opart, Lpart, ctx);

    // out = ctx @ wo, split-K(2) partials + add
    gemm_bt<1><<<dim3(2048 / 128, 2048 / 128, 2), 256, 0, stream>>>(
        ctx, woT, Pp, nullptr, nullptr, nullptr, nullptr, 2048, 2048, 1024);
    add_out<<<2048 * 2048 / 8 / 256, 256, 0, stream>>>(
        Pp, Pp + (size_t)2048 * 2048, out);
}

// Round 8
// 253.878 us; speedup vs baseline: 1.1070x; 1.0279x over previous
//
#include <hip/hip_runtime.h>

#define SEQ 2048
#define HID 2048
#define NH  32
#define NKV 8
#define HD  64

typedef _Float16 f16;
typedef __attribute__((ext_vector_type(4))) _Float16 f16x4;
typedef __attribute__((ext_vector_type(8))) _Float16 f16x8;
typedef __attribute__((ext_vector_type(4))) float    f32x4;

__device__ __forceinline__ f32x4 mfma_16x16x32(f16x8 a, f16x8 b, f32x4 c) {
    return __builtin_amdgcn_mfma_f32_16x16x32_f16(a, b, c, 0, 0, 0);
}

// async global->LDS, 16B per lane. Global address is PER-LANE (gather);
// LDS dest is wave-uniform base + lane*16 (contiguous).
__device__ __forceinline__ void async16(const void* g, void* l) {
    __builtin_amdgcn_global_load_lds(
        (const __attribute__((address_space(1))) void*)g,
        (__attribute__((address_space(3))) void*)l,
        16, 0, 0);
}

// ---------------- prep kernels ----------------

__global__ void cvt_f32_to_f16(const float* __restrict__ src, f16* __restrict__ dst) {
    int i = (blockIdx.x * 256 + threadIdx.x) * 4;
    float4 v = *(const float4*)(src + i);
    f16x4 o = { (f16)v.x, (f16)v.y, (f16)v.z, (f16)v.w };
    *(f16x4*)(dst + i) = o;
}

// All four weight transposes in one launch; route by blockIdx.z.
__global__ void transpose_all(const float* __restrict__ wq, const float* __restrict__ wk,
                              const float* __restrict__ wv, const float* __restrict__ wo,
                              f16* __restrict__ Wcat, f16* __restrict__ woT) {
    __shared__ float tile[32][33];
    int z = blockIdx.z;
    const float* src; f16* dst; int C;
    if      (z == 0) { src = wq; dst = Wcat;                         C = 2048; }
    else if (z == 1) { src = wk; dst = Wcat + (size_t)2048 * 2048;   C = 512;  }
    else if (z == 2) { src = wv; dst = Wcat + (size_t)2560 * 2048;   C = 512;  }
    else             { src = wo; dst = woT;                          C = 2048; }
    int c0 = blockIdx.x * 32, r0 = blockIdx.y * 32;
    if (c0 >= C) return;
    int tx = threadIdx.x, ty = threadIdx.y;
#pragma unroll
    for (int i = 0; i < 32; i += 8)
        tile[ty + i][tx] = src[(size_t)(r0 + ty + i) * C + c0 + tx];
    __syncthreads();
#pragma unroll
    for (int i = 0; i < 32; i += 8)
        dst[(size_t)(c0 + ty + i) * 2048 + r0 + tx] = (f16)tile[tx][ty + i];
}

// ---------------- GEMM: C[M,N] = A[M,K] @ BT[N,K]^T ----------------
// 64(M) x 128(N) tile, BK=32, 4 waves 2x2 (wave: 32 M x 64 N), dbuf staging,
// ONE barrier per K-tile. blockIdx.z = K-split (MODE 1 partials).
// MODE 0: fused QKV epilogue + RoPE (head = 64-aligned wave column, uniform).
// MODE 1: f16 row-major partial into Cp + z*2048*2048.
template <int MODE>
__global__ __launch_bounds__(256)
void gemm_bt(const f16* __restrict__ A, const f16* __restrict__ BT,
             f16* __restrict__ Cp, f16* __restrict__ Q, f16* __restrict__ Kk,
             f16* __restrict__ VT, const int* __restrict__ pos,
             int N, int Kstride, int Klen) {
    __shared__ f16 As[2][64 * 32];
    __shared__ f16 Bs[2][128 * 32];
    int t = threadIdx.x;
    int w = t >> 6, lane = t & 63, quad = lane >> 4, l15 = lane & 15;
    int wm = w >> 1, wn = w & 1;
    int m0 = blockIdx.y * 64, n0 = blockIdx.x * 128;
    size_t koff = (size_t)blockIdx.z * Klen;

    int srow  = t >> 2;        // 0..63
    int skoff = (t & 3) * 8;
    const f16* Ag = A  + (size_t)(m0 + srow) * Kstride + koff + skoff;
    const f16* Bg = BT + (size_t)(n0 + srow) * Kstride + koff + skoff;

    f32x4 acc[2][4] = {};

    // stage tile 0
    async16(Ag,                        &As[0][w * 512]);
    async16(Bg,                        &Bs[0][w * 512]);
    async16(Bg + (size_t)64 * Kstride, &Bs[0][2048 + w * 512]);
    __syncthreads();

    int b = 0;
    for (int kt = 32; kt <= Klen; kt += 32) {
        if (kt < Klen) {
            async16(Ag + kt,                        &As[b ^ 1][w * 512]);
            async16(Bg + kt,                        &Bs[b ^ 1][w * 512]);
            async16(Bg + (size_t)64 * Kstride + kt, &Bs[b ^ 1][2048 + w * 512]);
        }
        f16x8 af[2], bf[4];
#pragma unroll
        for (int mi = 0; mi < 2; mi++)
            af[mi] = *(const f16x8*)(&As[b][(wm * 32 + mi * 16 + l15) * 32 + quad * 8]);
#pragma unroll
        for (int ni = 0; ni < 4; ni++)
            bf[ni] = *(const f16x8*)(&Bs[b][(wn * 64 + ni * 16 + l15) * 32 + quad * 8]);
#pragma unroll
        for (int mi = 0; mi < 2; mi++)
#pragma unroll
            for (int ni = 0; ni < 4; ni++)
                acc[mi][ni] = mfma_16x16x32(af[mi], bf[ni], acc[mi][ni]);
        __syncthreads();
        b ^= 1;
    }

    int rb  = m0 + wm * 32 + quad * 4;
    int cbh = n0 + wn * 64;          // 64-aligned: one head per wave column
    if (MODE == 0) {
        if (cbh < (NH + NKV) * HD) {
            // ---- Q or K head: RoPE fused. d = ni*16+l15 (ni<2), partner ni+2.
            bool isQ = cbh < NH * HD;
            f16* dst = isQ ? (Q  + (size_t)(cbh >> 6) * SEQ * HD)
                           : (Kk + (size_t)((cbh - NH * HD) >> 6) * SEQ * HD);
            float scale = isQ ? 0.18033688011112042f : 1.0f;  // (1/8)*log2(e)
            float fr[2];
#pragma unroll
            for (int ni = 0; ni < 2; ni++)
                fr[ni] = __builtin_amdgcn_exp2f(
                    (float)(ni * 16 + l15) * -0.41524101186092029f); // -log2(1e4)/32
#pragma unroll
            for (int mi = 0; mi < 2; mi++)
#pragma unroll
                for (int r = 0; r < 4; r++) {
                    int row = rb + mi * 16 + r;
                    float pv = (float)pos[row];
#pragma unroll
                    for (int ni = 0; ni < 2; ni++) {
                        float sn, cs;
                        __sincosf(pv * fr[ni], &sn, &cs);
                        float x1 = acc[mi][ni][r], x2 = acc[mi][ni + 2][r];
                        int d = ni * 16 + l15;
                        dst[(size_t)row * HD + d]      = (f16)(scale * (x1 * cs - x2 * sn));
                        dst[(size_t)row * HD + d + 32] = (f16)(scale * (x2 * cs + x1 * sn));
                    }
                }
        } else {
            // ---- V^T passthrough: VT[c2][s], 4 rows contiguous in s.
#pragma unroll
            for (int mi = 0; mi < 2; mi++)
#pragma unroll
                for (int ni = 0; ni < 4; ni++) {
                    int c2 = cbh - (NH + NKV) * HD + ni * 16 + l15;
                    f16x4 v4 = { (f16)acc[mi][ni][0], (f16)acc[mi][ni][1],
                                 (f16)acc[mi][ni][2], (f16)acc[mi][ni][3] };
                    *(f16x4*)(VT + (size_t)c2 * SEQ + rb + mi * 16) = v4;
                }
        }
    } else {
        f16* Co = Cp + (size_t)blockIdx.z * 2048 * 2048;
#pragma unroll
        for (int mi = 0; mi < 2; mi++)
#pragma unroll
            for (int ni = 0; ni < 4; ni++)
#pragma unroll
                for (int r = 0; r < 4; r++)
                    Co[(size_t)(rb + mi * 16 + r) * N + cbh + ni * 16 + l15] =
                        (f16)acc[mi][ni][r];
    }
}

// ---------------- fused flash attention, P kept in registers ----------------
// grid (SEQ/128, NH, 2), block 256 = 4 waves; wave owns 32 q-rows; split z owns
// 16 of 32 key tiles. K staged with PERMUTED key rows (g = 32*(ni>>1) + 8*quad
// + 4*(ni&1) + r) so the S^T C-layout IS the PV B-operand layout: P never
// touches LDS. PV computes O^T = V^T @ P with A = V^T from LDS. LDS = 32 KB.
__global__ __launch_bounds__(256)
void attn_fused(const f16* __restrict__ Qb, const f16* __restrict__ Kb,
                const f16* __restrict__ VTb, const float* __restrict__ mask,
                f16* __restrict__ Opart, float* __restrict__ Lpart) {
    __shared__ f16 Ks[2][64 * 64];
    __shared__ f16 Vs[2][64 * 64];

    int t = threadIdx.x, w = t >> 6, lane = t & 63, quad = lane >> 4, l15 = lane & 15;
    int h = blockIdx.y, kvh = h >> 2, split = blockIdx.z;
    int qbase = blockIdx.x * 128 + w * 32;
    int key0  = split * (SEQ / 2);
    const f16* Qh = Qb  + (size_t)h   * SEQ * HD;
    const f16* Kh = Kb  + (size_t)kvh * SEQ * HD;
    const f16* Vh = VTb + (size_t)kvh * HD * SEQ;
    int sw = l15 & 7;
    const float LOG2E = 1.4426950408889634f;

    // staging lane geometry: 8 rows x 8 chunks per async16, XOR-swizzled chunks.
    // K rows permuted: LDS row rr = w*16 + r8 holds key g = 32*(w>>1) + 4*(w&1)
    // + 8*(r8>>2) + (r8&3); second async16 covers rr+8 -> g+16.
    int r8 = lane >> 3;
    int cc = (lane & 7) ^ r8;
    int gk = 32 * (w >> 1) + 4 * (w & 1) + 8 * (r8 >> 2) + (r8 & 3);
    const f16* kg0 = Kh + (size_t)(key0 + gk) * HD + cc * 8;
    const f16* kg1 = kg0 + (size_t)16 * HD;
    const f16* vg0 = Vh + (size_t)(w * 16 + r8) * SEQ + key0 + cc * 8;
    const f16* vg1 = vg0 + 8 * SEQ;
    int lr0 = (w * 16) * 64, lr1 = (w * 16 + 8) * 64;

    async16(kg0, &Ks[0][lr0]);
    async16(kg1, &Ks[0][lr1]);
    async16(vg0, &Vs[0][lr0]);
    async16(vg1, &Vs[0][lr1]);

    // ---- Q fragments (persistent): B-operand of S^T, n = q ----
    f16x8 bq[2][2];
#pragma unroll
    for (int qg = 0; qg < 2; qg++)
#pragma unroll
        for (int ks = 0; ks < 2; ks++)
            bq[qg][ks] = *(const f16x8*)(Qh + (size_t)(qbase + qg * 16 + l15) * HD
                                            + ks * 32 + quad * 8);

    f32x4 o[4][2] = {};          // O^T: [d-tile][q-group]
    float l_part[2] = {0.f, 0.f};

    __syncthreads();
    int b = 0;

    for (int ktl = 0; ktl < SEQ / 128; ktl++) {
        if (ktl + 1 < SEQ / 128) {
            kg0 += 64 * HD; kg1 += 64 * HD; vg0 += 64; vg1 += 64;
            async16(kg0, &Ks[b ^ 1][lr0]);
            async16(kg1, &Ks[b ^ 1][lr1]);
            async16(vg0, &Vs[b ^ 1][lr0]);
            async16(vg1, &Vs[b ^ 1][lr1]);
        }
        const f16* Kb_ = &Ks[b][0];
        const f16* Vb_ = &Vs[b][0];

        // ---- S^T = K @ Q^T (keys in permuted order) ----
        f32x4 st[4][2] = {};
#pragma unroll
        for (int ni = 0; ni < 4; ni++) {
            const f16* kr = Kb_ + (ni * 16 + l15) * 64;
            f16x8 ak0 = *(const f16x8*)(kr + (quad ^ sw) * 8);
            f16x8 ak1 = *(const f16x8*)(kr + ((4 | quad) ^ sw) * 8);
#pragma unroll
            for (int qg = 0; qg < 2; qg++) {
                st[ni][qg] = mfma_16x16x32(ak0, bq[qg][0], st[ni][qg]);
                st[ni][qg] = mfma_16x16x32(ak1, bq[qg][1], st[ni][qg]);
            }
        }
        // ---- exp2 (+mask at permuted key), pack P into PV B-frags (in-lane) ----
        f16x8 pb[2][2];   // [qg][ks]
#pragma unroll
        for (int ni = 0; ni < 4; ni++) {
            float4 m4 = *(const float4*)(mask + key0 + ktl * 64
                                         + (ni >> 1) * 32 + (ni & 1) * 4 + quad * 8);
#pragma unroll
            for (int qg = 0; qg < 2; qg++) {
#pragma unroll
                for (int r = 0; r < 4; r++) {
                    float p = __builtin_amdgcn_exp2f(
                        fmaf((&m4.x)[r], LOG2E, st[ni][qg][r]));
                    l_part[qg] += p;
                    pb[qg][ni >> 1][(ni & 1) * 4 + r] = (f16)p;
                }
            }
        }
        // ---- O^T += V^T @ P : A = V^T rows d, B = pb (registers) ----
#pragma unroll
        for (int dt = 0; dt < 4; dt++) {
            const f16* vr = Vb_ + (dt * 16 + l15) * 64;
            f16x8 av0 = *(const f16x8*)(vr + (quad ^ sw) * 8);
            f16x8 av1 = *(const f16x8*)(vr + ((4 | quad) ^ sw) * 8);
#pragma unroll
            for (int qg = 0; qg < 2; qg++) {
                o[dt][qg] = mfma_16x16x32(av0, pb[qg][0], o[dt][qg]);
                o[dt][qg] = mfma_16x16x32(av1, pb[qg][1], o[dt][qg]);
            }
        }
        __syncthreads();
        b ^= 1;
    }

    // ---- partial l: reduce over quads -> full sum for q = qg*16+l15 ----
    float lf[2];
#pragma unroll
    for (int qg = 0; qg < 2; qg++) {
        float v = l_part[qg];
        v += __shfl_xor(v, 16);
        v += __shfl_xor(v, 32);
        lf[qg] = v;
    }
    if (quad == 0) {
#pragma unroll
        for (int qg = 0; qg < 2; qg++)
            Lpart[((size_t)split * NH + h) * SEQ + qbase + qg * 16 + l15] = lf[qg];
    }
    // ---- unnormalized O^T partial: lane holds d = dt*16+quad*4+r, q = qg*16+l15
    f16* Op = Opart + ((size_t)split * NH + h) * SEQ * HD;
#pragma unroll
    for (int dt = 0; dt < 4; dt++)
#pragma unroll
        for (int qg = 0; qg < 2; qg++) {
            f16x4 v4 = { (f16)o[dt][qg][0], (f16)o[dt][qg][1],
                         (f16)o[dt][qg][2], (f16)o[dt][qg][3] };
            *(f16x4*)(Op + (size_t)(qbase + qg * 16 + l15) * HD
                         + dt * 16 + quad * 4) = v4;
        }
}

// ---------------- combine: ctx[row][h*64+d] = (O0+O1)/(l0+l1) ----------------
__global__ void attn_combine(const f16* __restrict__ O, const float* __restrict__ L,
                             f16* __restrict__ ctx) {
    int idx = blockIdx.x * 256 + threadIdx.x;   // one f16x4 per thread
    int c4  = idx & 511;
    int row = idx >> 9;
    int col = c4 * 4;
    int h   = col >> 6;
    float l = L[(size_t)h * SEQ + row] + L[(size_t)(NH + h) * SEQ + row];
    const f16* o0 = O + ((size_t)h * SEQ + row) * HD + (col & 63);
    const f16* o1 = o0 + (size_t)NH * SEQ * HD;
    f16x4 a = *(const f16x4*)o0, b = *(const f16x4*)o1;
    float inv = 1.0f / l;
    f16x4 r;
#pragma unroll
    for (int j = 0; j < 4; j++)
        r[j] = (f16)(((float)a[j] + (float)b[j]) * inv);
    *(f16x4*)(ctx + (size_t)row * (NH * HD) + col) = r;
}

// ---------------- combine: out = P0 + P1 (fp32) ----------------
__global__ void add_out(const f16* __restrict__ P0, const f16* __restrict__ P1,
                        float* __restrict__ out) {
    int i = (blockIdx.x * 256 + threadIdx.x) * 8;
    f16x8 a = *(const f16x8*)(P0 + i);
    f16x8 b = *(const f16x8*)(P1 + i);
    float4 o0, o1;
    o0.x = (float)a[0] + (float)b[0]; o0.y = (float)a[1] + (float)b[1];
    o0.z = (float)a[2] + (float)b[2]; o0.w = (float)a[3] + (float)b[3];
    o1.x = (float)a[4] + (float)b[4]; o1.y = (float)a[5] + (float)b[5];
    o1.z = (float)a[6] + (float)b[6]; o1.w = (float)a[7] + (float)b[7];
    *(float4*)(out + i)     = o0;
    *(float4*)(out + i + 4) = o1;
}

// ---------------- launch ----------------
extern "C" void kernel_launch(void* const* d_in, const int* in_sizes, int n_in,
                              void* d_out, int out_size, void* d_ws, size_t ws_size,
                              hipStream_t stream) {
    const float* x    = (const float*)d_in[0];
    const float* mask = (const float*)d_in[1];
    const int*   pos  = (const int*)  d_in[2];
    const float* wq   = (const float*)d_in[3];
    const float* wk   = (const float*)d_in[4];
    const float* wv   = (const float*)d_in[5];
    const float* wo   = (const float*)d_in[6];
    float* out = (float*)d_out;

    char* ws = (char*)d_ws;
    // phase 1-2: xb [0,8M), Wcat [8M,20M), woT [20M,28M), Qb [28M,36M),
    //            Kb [36M,38M), VTb [38M,40M)
    // phase 3-4: Opart [0,16M) (xb/Wcat dead), Lpart [16M,16.5M),
    //            ctx [28M,36M) (Qb region)
    // phase 5-6: Pp [0,16M) (Opart dead), woT/ctx still live
    f16*   xb    = (f16*)(ws);
    f16*   Wcat  = (f16*)(ws + ((size_t)8  << 20));
    f16*   woT   = (f16*)(ws + ((size_t)20 << 20));
    f16*   Qb    = (f16*)(ws + ((size_t)28 << 20));
    f16*   Kb    = (f16*)(ws + ((size_t)36 << 20));
    f16*   VTb   = (f16*)(ws + ((size_t)38 << 20));
    f16*   Opart = (f16*)(ws);
    float* Lpart = (float*)(ws + ((size_t)16 << 20));
    f16*   ctx   = (f16*)(ws + ((size_t)28 << 20));
    f16*   Pp    = (f16*)(ws);

    cvt_f32_to_f16<<<HID * SEQ / 1024, 256, 0, stream>>>(x, xb);
    transpose_all<<<dim3(64, 64, 4), dim3(32, 8), 0, stream>>>(
        wq, wk, wv, wo, Wcat, woT);

    // fused Q/K/V projection + RoPE epilogue: C[2048,3072] = xb @ Wcat^T
    gemm_bt<0><<<dim3(3072 / 128, 2048 / 64, 1), 256, 0, stream>>>(
        xb, Wcat, nullptr, Qb, Kb, VTb, pos, 3072, 2048, 2048);

    attn_fused<<<dim3(SEQ / 128, NH, 2), 256, 0, stream>>>(
        Qb, Kb, VTb, mask, Opart, Lpart);
    attn_combine<<<SEQ * NH * HD / 4 / 256, 256, 0, stream>>>(Opart, Lpart, ctx);

    // out = ctx @ wo, split-K(2) partials + add
    gemm_bt<1><<<dim3(2048 / 128, 2048 / 64, 2), 256, 0, stream>>>(
        ctx, woT, Pp, nullptr, nullptr, nullptr, nullptr, 2048, 2048, 1024);
    add_out<<<2048 * 2048 / 8 / 256, 256, 0, stream>>>(
        Pp, Pp + (size_t)2048 * 2048, out);
}

// Round 9
// 241.947 us; speedup vs baseline: 1.1616x; 1.0493x over previous
//
#include <hip/hip_runtime.h>

#define SEQ 2048
#define HID 2048
#define NH  32
#define NKV 8
#define HD  64

typedef _Float16 f16;
typedef __attribute__((ext_vector_type(4))) _Float16 f16x4;
typedef __attribute__((ext_vector_type(8))) _Float16 f16x8;
typedef __attribute__((ext_vector_type(4))) float    f32x4;

__device__ __forceinline__ f32x4 mfma_16x16x32(f16x8 a, f16x8 b, f32x4 c) {
    return __builtin_amdgcn_mfma_f32_16x16x32_f16(a, b, c, 0, 0, 0);
}

// async global->LDS, 16B per lane. Global address is PER-LANE (gather);
// LDS dest is wave-uniform base + lane*16 (contiguous).
__device__ __forceinline__ void async16(const void* g, void* l) {
    __builtin_amdgcn_global_load_lds(
        (const __attribute__((address_space(1))) void*)g,
        (__attribute__((address_space(3))) void*)l,
        16, 0, 0);
}

// ---------------- prep: 4 weight transposes + x cvt in ONE launch ----------------
// z<4: dst[c][r] = (f16)src[r][c];  z==4: xb = (f16)x (flat copy-convert).
__global__ void prep_all(const float* __restrict__ x,
                         const float* __restrict__ wq, const float* __restrict__ wk,
                         const float* __restrict__ wv, const float* __restrict__ wo,
                         f16* __restrict__ xb,
                         f16* __restrict__ Wcat, f16* __restrict__ woT) {
    __shared__ float tile[32][33];
    int z = blockIdx.z;
    int tx = threadIdx.x, ty = threadIdx.y;
    if (z == 4) {   // cvt: 4096 blocks x 256 threads x 4 elems = 2048*2048
        int idx = (blockIdx.y * 64 + blockIdx.x) * 256 + ty * 32 + tx;
        int i = idx * 4;
        float4 v = *(const float4*)(x + i);
        f16x4 o = { (f16)v.x, (f16)v.y, (f16)v.z, (f16)v.w };
        *(f16x4*)(xb + i) = o;
        return;
    }
    const float* src; f16* dst; int C;
    if      (z == 0) { src = wq; dst = Wcat;                         C = 2048; }
    else if (z == 1) { src = wk; dst = Wcat + (size_t)2048 * 2048;   C = 512;  }
    else if (z == 2) { src = wv; dst = Wcat + (size_t)2560 * 2048;   C = 512;  }
    else             { src = wo; dst = woT;                          C = 2048; }
    int c0 = blockIdx.x * 32, r0 = blockIdx.y * 32;
    if (c0 >= C) return;
#pragma unroll
    for (int i = 0; i < 32; i += 8)
        tile[ty + i][tx] = src[(size_t)(r0 + ty + i) * C + c0 + tx];
    __syncthreads();
#pragma unroll
    for (int i = 0; i < 32; i += 8)
        dst[(size_t)(c0 + ty + i) * 2048 + r0 + tx] = (f16)tile[tx][ty + i];
}

// ---------------- GEMM: C[M,N] = A[M,K] @ BT[N,K]^T ----------------
// 64(M) x 128(N) tile, BK=32, 4 waves 2x2 (wave: 32 M x 64 N), dbuf staging,
// ONE barrier per K-tile.
// MODE 0: fused QKV epilogue + RoPE (head = 64-aligned wave column, uniform).
// MODE 1: fp32 row-major direct into Cf.
template <int MODE>
__global__ __launch_bounds__(256)
void gemm_bt(const f16* __restrict__ A, const f16* __restrict__ BT,
             float* __restrict__ Cf, f16* __restrict__ Q, f16* __restrict__ Kk,
             f16* __restrict__ VT, const int* __restrict__ pos, int N, int K) {
    __shared__ f16 As[2][64 * 32];
    __shared__ f16 Bs[2][128 * 32];
    int t = threadIdx.x;
    int w = t >> 6, lane = t & 63, quad = lane >> 4, l15 = lane & 15;
    int wm = w >> 1, wn = w & 1;
    int m0 = blockIdx.y * 64, n0 = blockIdx.x * 128;

    int srow  = t >> 2;        // 0..63
    int skoff = (t & 3) * 8;
    const f16* Ag = A  + (size_t)(m0 + srow) * K + skoff;
    const f16* Bg = BT + (size_t)(n0 + srow) * K + skoff;

    f32x4 acc[2][4] = {};

    // stage tile 0
    async16(Ag,                  &As[0][w * 512]);
    async16(Bg,                  &Bs[0][w * 512]);
    async16(Bg + (size_t)64 * K, &Bs[0][2048 + w * 512]);
    __syncthreads();

    int b = 0;
    for (int kt = 32; kt <= K; kt += 32) {
        if (kt < K) {
            async16(Ag + kt,                  &As[b ^ 1][w * 512]);
            async16(Bg + kt,                  &Bs[b ^ 1][w * 512]);
            async16(Bg + (size_t)64 * K + kt, &Bs[b ^ 1][2048 + w * 512]);
        }
        f16x8 af[2], bf[4];
#pragma unroll
        for (int mi = 0; mi < 2; mi++)
            af[mi] = *(const f16x8*)(&As[b][(wm * 32 + mi * 16 + l15) * 32 + quad * 8]);
#pragma unroll
        for (int ni = 0; ni < 4; ni++)
            bf[ni] = *(const f16x8*)(&Bs[b][(wn * 64 + ni * 16 + l15) * 32 + quad * 8]);
#pragma unroll
        for (int mi = 0; mi < 2; mi++)
#pragma unroll
            for (int ni = 0; ni < 4; ni++)
                acc[mi][ni] = mfma_16x16x32(af[mi], bf[ni], acc[mi][ni]);
        __syncthreads();
        b ^= 1;
    }

    int rb  = m0 + wm * 32 + quad * 4;
    int cbh = n0 + wn * 64;          // 64-aligned: one head per wave column
    if (MODE == 0) {
        if (cbh < (NH + NKV) * HD) {
            // ---- Q or K head: RoPE fused. d = ni*16+l15 (ni<2), partner ni+2.
            bool isQ = cbh < NH * HD;
            f16* dst = isQ ? (Q  + (size_t)(cbh >> 6) * SEQ * HD)
                           : (Kk + (size_t)((cbh - NH * HD) >> 6) * SEQ * HD);
            float scale = isQ ? 0.18033688011112042f : 1.0f;  // (1/8)*log2(e)
            float fr[2];
#pragma unroll
            for (int ni = 0; ni < 2; ni++)
                fr[ni] = __builtin_amdgcn_exp2f(
                    (float)(ni * 16 + l15) * -0.41524101186092029f); // -log2(1e4)/32
#pragma unroll
            for (int mi = 0; mi < 2; mi++)
#pragma unroll
                for (int r = 0; r < 4; r++) {
                    int row = rb + mi * 16 + r;
                    float pv = (float)pos[row];
#pragma unroll
                    for (int ni = 0; ni < 2; ni++) {
                        float sn, cs;
                        __sincosf(pv * fr[ni], &sn, &cs);
                        float x1 = acc[mi][ni][r], x2 = acc[mi][ni + 2][r];
                        int d = ni * 16 + l15;
                        dst[(size_t)row * HD + d]      = (f16)(scale * (x1 * cs - x2 * sn));
                        dst[(size_t)row * HD + d + 32] = (f16)(scale * (x2 * cs + x1 * sn));
                    }
                }
        } else {
            // ---- V^T passthrough: VT[c2][s], 4 rows contiguous in s.
#pragma unroll
            for (int mi = 0; mi < 2; mi++)
#pragma unroll
                for (int ni = 0; ni < 4; ni++) {
                    int c2 = cbh - (NH + NKV) * HD + ni * 16 + l15;
                    f16x4 v4 = { (f16)acc[mi][ni][0], (f16)acc[mi][ni][1],
                                 (f16)acc[mi][ni][2], (f16)acc[mi][ni][3] };
                    *(f16x4*)(VT + (size_t)c2 * SEQ + rb + mi * 16) = v4;
                }
        }
    } else {
#pragma unroll
        for (int mi = 0; mi < 2; mi++)
#pragma unroll
            for (int ni = 0; ni < 4; ni++)
#pragma unroll
                for (int r = 0; r < 4; r++)
                    Cf[(size_t)(rb + mi * 16 + r) * N + cbh + ni * 16 + l15] =
                        acc[mi][ni][r];
    }
}

// ---------------- fused flash attention, P in registers, direct ctx ----------------
// grid (SEQ/128, NH) = 512 blocks, 4 waves; wave owns 32 q-rows, full 2048 keys.
// K staged with PERMUTED key rows so the S^T C-layout IS the PV B-operand
// layout (P never touches LDS). PV computes O^T = V^T @ P. LDS = 32 KB.
// Epilogue: l lives at the same lane as o's q -> in-lane normalize, f16x4 store.
__global__ __launch_bounds__(256)
void attn_fused(const f16* __restrict__ Qb, const f16* __restrict__ Kb,
                const f16* __restrict__ VTb, const float* __restrict__ mask,
                f16* __restrict__ ctx) {
    __shared__ f16 Ks[2][64 * 64];
    __shared__ f16 Vs[2][64 * 64];

    int t = threadIdx.x, w = t >> 6, lane = t & 63, quad = lane >> 4, l15 = lane & 15;
    int h = blockIdx.y, kvh = h >> 2;
    int qbase = blockIdx.x * 128 + w * 32;
    const f16* Qh = Qb  + (size_t)h   * SEQ * HD;
    const f16* Kh = Kb  + (size_t)kvh * SEQ * HD;
    const f16* Vh = VTb + (size_t)kvh * HD * SEQ;
    int sw = l15 & 7;
    const float LOG2E = 1.4426950408889634f;

    // staging lane geometry: 8 rows x 8 chunks per async16, XOR-swizzled chunks.
    // K rows permuted: LDS row rr = w*16 + r8 holds key g = 32*(w>>1) + 4*(w&1)
    // + 8*(r8>>2) + (r8&3); second async16 covers rr+8 -> g+16.
    int r8 = lane >> 3;
    int cc = (lane & 7) ^ r8;
    int gk = 32 * (w >> 1) + 4 * (w & 1) + 8 * (r8 >> 2) + (r8 & 3);
    const f16* kg0 = Kh + (size_t)gk * HD + cc * 8;
    const f16* kg1 = kg0 + (size_t)16 * HD;
    const f16* vg0 = Vh + (size_t)(w * 16 + r8) * SEQ + cc * 8;
    const f16* vg1 = vg0 + 8 * SEQ;
    int lr0 = (w * 16) * 64, lr1 = (w * 16 + 8) * 64;

    async16(kg0, &Ks[0][lr0]);
    async16(kg1, &Ks[0][lr1]);
    async16(vg0, &Vs[0][lr0]);
    async16(vg1, &Vs[0][lr1]);

    // ---- Q fragments (persistent): B-operand of S^T, n = q ----
    f16x8 bq[2][2];
#pragma unroll
    for (int qg = 0; qg < 2; qg++)
#pragma unroll
        for (int ks = 0; ks < 2; ks++)
            bq[qg][ks] = *(const f16x8*)(Qh + (size_t)(qbase + qg * 16 + l15) * HD
                                            + ks * 32 + quad * 8);

    f32x4 o[4][2] = {};          // O^T: [d-tile][q-group]
    float l_part[2] = {0.f, 0.f};

    __syncthreads();
    int b = 0;

    for (int ktl = 0; ktl < SEQ / 64; ktl++) {
        if (ktl + 1 < SEQ / 64) {
            kg0 += 64 * HD; kg1 += 64 * HD; vg0 += 64; vg1 += 64;
            async16(kg0, &Ks[b ^ 1][lr0]);
            async16(kg1, &Ks[b ^ 1][lr1]);
            async16(vg0, &Vs[b ^ 1][lr0]);
            async16(vg1, &Vs[b ^ 1][lr1]);
        }
        const f16* Kb_ = &Ks[b][0];
        const f16* Vb_ = &Vs[b][0];

        // ---- S^T = K @ Q^T (keys in permuted order) ----
        f32x4 st[4][2] = {};
#pragma unroll
        for (int ni = 0; ni < 4; ni++) {
            const f16* kr = Kb_ + (ni * 16 + l15) * 64;
            f16x8 ak0 = *(const f16x8*)(kr + (quad ^ sw) * 8);
            f16x8 ak1 = *(const f16x8*)(kr + ((4 | quad) ^ sw) * 8);
#pragma unroll
            for (int qg = 0; qg < 2; qg++) {
                st[ni][qg] = mfma_16x16x32(ak0, bq[qg][0], st[ni][qg]);
                st[ni][qg] = mfma_16x16x32(ak1, bq[qg][1], st[ni][qg]);
            }
        }
        // ---- exp2 (+mask at permuted key), pack P into PV B-frags (in-lane) ----
        f16x8 pb[2][2];   // [qg][ks]
#pragma unroll
        for (int ni = 0; ni < 4; ni++) {
            float4 m4 = *(const float4*)(mask + ktl * 64
                                         + (ni >> 1) * 32 + (ni & 1) * 4 + quad * 8);
#pragma unroll
            for (int qg = 0; qg < 2; qg++) {
#pragma unroll
                for (int r = 0; r < 4; r++) {
                    float p = __builtin_amdgcn_exp2f(
                        fmaf((&m4.x)[r], LOG2E, st[ni][qg][r]));
                    l_part[qg] += p;
                    pb[qg][ni >> 1][(ni & 1) * 4 + r] = (f16)p;
                }
            }
        }
        // ---- O^T += V^T @ P : A = V^T rows d, B = pb (registers) ----
#pragma unroll
        for (int dt = 0; dt < 4; dt++) {
            const f16* vr = Vb_ + (dt * 16 + l15) * 64;
            f16x8 av0 = *(const f16x8*)(vr + (quad ^ sw) * 8);
            f16x8 av1 = *(const f16x8*)(vr + ((4 | quad) ^ sw) * 8);
#pragma unroll
            for (int qg = 0; qg < 2; qg++) {
                o[dt][qg] = mfma_16x16x32(av0, pb[qg][0], o[dt][qg]);
                o[dt][qg] = mfma_16x16x32(av1, pb[qg][1], o[dt][qg]);
            }
        }
        __syncthreads();
        b ^= 1;
    }

    // ---- l: reduce over quads; every lane then holds l for q = qg*16+l15,
    //      which is exactly the q of its o[*][qg] accumulators -> in-lane div.
    float linv[2];
#pragma unroll
    for (int qg = 0; qg < 2; qg++) {
        float v = l_part[qg];
        v += __shfl_xor(v, 16);
        v += __shfl_xor(v, 32);
        linv[qg] = 1.0f / v;
    }
    // ---- ctx[row][h*64+d]: lane holds d = dt*16+quad*4+r, q = qg*16+l15 ----
#pragma unroll
    for (int dt = 0; dt < 4; dt++)
#pragma unroll
        for (int qg = 0; qg < 2; qg++) {
            f16x4 v4 = { (f16)(o[dt][qg][0] * linv[qg]),
                         (f16)(o[dt][qg][1] * linv[qg]),
                         (f16)(o[dt][qg][2] * linv[qg]),
                         (f16)(o[dt][qg][3] * linv[qg]) };
            *(f16x4*)(ctx + (size_t)(qbase + qg * 16 + l15) * (NH * HD)
                          + h * 64 + dt * 16 + quad * 4) = v4;
        }
}

// ---------------- launch ----------------
extern "C" void kernel_launch(void* const* d_in, const int* in_sizes, int n_in,
                              void* d_out, int out_size, void* d_ws, size_t ws_size,
                              hipStream_t stream) {
    const float* x    = (const float*)d_in[0];
    const float* mask = (const float*)d_in[1];
    const int*   pos  = (const int*)  d_in[2];
    const float* wq   = (const float*)d_in[3];
    const float* wk   = (const float*)d_in[4];
    const float* wv   = (const float*)d_in[5];
    const float* wo   = (const float*)d_in[6];
    float* out = (float*)d_out;

    char* ws = (char*)d_ws;
    // xb [0,8M) dead after QKV -> ctx reuses [0,8M).
    // Wcat [8M,20M), woT [20M,28M), Qb [28M,36M), Kb [36M,38M), VTb [38M,40M)
    f16* xb   = (f16*)(ws);
    f16* ctx  = (f16*)(ws);
    f16* Wcat = (f16*)(ws + ((size_t)8  << 20));
    f16* woT  = (f16*)(ws + ((size_t)20 << 20));
    f16* Qb   = (f16*)(ws + ((size_t)28 << 20));
    f16* Kb   = (f16*)(ws + ((size_t)36 << 20));
    f16* VTb  = (f16*)(ws + ((size_t)38 << 20));

    prep_all<<<dim3(64, 64, 5), dim3(32, 8), 0, stream>>>(
        x, wq, wk, wv, wo, xb, Wcat, woT);

    // fused Q/K/V projection + RoPE epilogue: C[2048,3072] = xb @ Wcat^T
    gemm_bt<0><<<dim3(3072 / 128, 2048 / 64), 256, 0, stream>>>(
        xb, Wcat, nullptr, Qb, Kb, VTb, pos, 3072, 2048);

    attn_fused<<<dim3(SEQ / 128, NH), 256, 0, stream>>>(
        Qb, Kb, VTb, mask, ctx);

    // out = ctx @ wo (fp32 direct)
    gemm_bt<1><<<dim3(2048 / 128, 2048 / 64), 256, 0, stream>>>(
        ctx, woT, out, nullptr, nullptr, nullptr, nullptr, 2048, 2048);
}

// Round 10
// 233.448 us; speedup vs baseline: 1.2039x; 1.0364x over previous
//
#include <hip/hip_runtime.h>

#define SEQ 2048
#define HID 2048
#define NH  32
#define NKV 8
#define HD  64

typedef _Float16 f16;
typedef __attribute__((ext_vector_type(4))) _Float16 f16x4;
typedef __attribute__((ext_vector_type(8))) _Float16 f16x8;
typedef __attribute__((ext_vector_type(4))) float    f32x4;

__device__ __forceinline__ f32x4 mfma_16x16x32(f16x8 a, f16x8 b, f32x4 c) {
    return __builtin_amdgcn_mfma_f32_16x16x32_f16(a, b, c, 0, 0, 0);
}

// async global->LDS, 16B per lane. Global address is PER-LANE (gather);
// LDS dest is wave-uniform base + lane*16 (contiguous).
__device__ __forceinline__ void async16(const void* g, void* l) {
    __builtin_amdgcn_global_load_lds(
        (const __attribute__((address_space(1))) void*)g,
        (__attribute__((address_space(3))) void*)l,
        16, 0, 0);
}

// ---------------- prep: 4 weight transposes + x cvt in ONE launch ----------------
// z<4: dst[c][r] = (f16)src[r][c];  z==4: xb = (f16)x (flat copy-convert).
__global__ void prep_all(const float* __restrict__ x,
                         const float* __restrict__ wq, const float* __restrict__ wk,
                         const float* __restrict__ wv, const float* __restrict__ wo,
                         f16* __restrict__ xb,
                         f16* __restrict__ Wcat, f16* __restrict__ woT) {
    __shared__ float tile[32][33];
    int z = blockIdx.z;
    int tx = threadIdx.x, ty = threadIdx.y;
    if (z == 4) {   // cvt: 4096 blocks x 256 threads x 4 elems = 2048*2048
        int idx = (blockIdx.y * 64 + blockIdx.x) * 256 + ty * 32 + tx;
        int i = idx * 4;
        float4 v = *(const float4*)(x + i);
        f16x4 o = { (f16)v.x, (f16)v.y, (f16)v.z, (f16)v.w };
        *(f16x4*)(xb + i) = o;
        return;
    }
    const float* src; f16* dst; int C;
    if      (z == 0) { src = wq; dst = Wcat;                         C = 2048; }
    else if (z == 1) { src = wk; dst = Wcat + (size_t)2048 * 2048;   C = 512;  }
    else if (z == 2) { src = wv; dst = Wcat + (size_t)2560 * 2048;   C = 512;  }
    else             { src = wo; dst = woT;                          C = 2048; }
    int c0 = blockIdx.x * 32, r0 = blockIdx.y * 32;
    if (c0 >= C) return;
#pragma unroll
    for (int i = 0; i < 32; i += 8)
        tile[ty + i][tx] = src[(size_t)(r0 + ty + i) * C + c0 + tx];
    __syncthreads();
#pragma unroll
    for (int i = 0; i < 32; i += 8)
        dst[(size_t)(c0 + ty + i) * 2048 + r0 + tx] = (f16)tile[tx][ty + i];
}

// ---------------- GEMM: C[M,N] = A[M,K] @ BT[N,K]^T ----------------
// 64(M) x 128(N) tile, BK=32, 4 waves 2x2 (wave: 32 M x 64 N), dbuf staging,
// ONE barrier per K-tile.
// MODE 0: fused QKV epilogue + RoPE; V^T scaled by em[s] = exp2(mask[s]*log2e)
//         (exact softmax-mask folding: exp(s+m) = exp(s)*em).
// MODE 1: fp32 row-major direct into Cf.
template <int MODE>
__global__ __launch_bounds__(256)
void gemm_bt(const f16* __restrict__ A, const f16* __restrict__ BT,
             float* __restrict__ Cf, f16* __restrict__ Q, f16* __restrict__ Kk,
             f16* __restrict__ VT, const int* __restrict__ pos,
             const float* __restrict__ mask, int N, int K) {
    __shared__ f16 As[2][64 * 32];
    __shared__ f16 Bs[2][128 * 32];
    int t = threadIdx.x;
    int w = t >> 6, lane = t & 63, quad = lane >> 4, l15 = lane & 15;
    int wm = w >> 1, wn = w & 1;
    int m0 = blockIdx.y * 64, n0 = blockIdx.x * 128;

    int srow  = t >> 2;        // 0..63
    int skoff = (t & 3) * 8;
    const f16* Ag = A  + (size_t)(m0 + srow) * K + skoff;
    const f16* Bg = BT + (size_t)(n0 + srow) * K + skoff;

    f32x4 acc[2][4] = {};

    // stage tile 0
    async16(Ag,                  &As[0][w * 512]);
    async16(Bg,                  &Bs[0][w * 512]);
    async16(Bg + (size_t)64 * K, &Bs[0][2048 + w * 512]);
    __syncthreads();

    int b = 0;
    for (int kt = 32; kt <= K; kt += 32) {
        if (kt < K) {
            async16(Ag + kt,                  &As[b ^ 1][w * 512]);
            async16(Bg + kt,                  &Bs[b ^ 1][w * 512]);
            async16(Bg + (size_t)64 * K + kt, &Bs[b ^ 1][2048 + w * 512]);
        }
        f16x8 af[2], bf[4];
#pragma unroll
        for (int mi = 0; mi < 2; mi++)
            af[mi] = *(const f16x8*)(&As[b][(wm * 32 + mi * 16 + l15) * 32 + quad * 8]);
#pragma unroll
        for (int ni = 0; ni < 4; ni++)
            bf[ni] = *(const f16x8*)(&Bs[b][(wn * 64 + ni * 16 + l15) * 32 + quad * 8]);
#pragma unroll
        for (int mi = 0; mi < 2; mi++)
#pragma unroll
            for (int ni = 0; ni < 4; ni++)
                acc[mi][ni] = mfma_16x16x32(af[mi], bf[ni], acc[mi][ni]);
        __syncthreads();
        b ^= 1;
    }

    int rb  = m0 + wm * 32 + quad * 4;
    int cbh = n0 + wn * 64;          // 64-aligned: one head per wave column
    if (MODE == 0) {
        if (cbh < (NH + NKV) * HD) {
            // ---- Q or K head: RoPE fused. d = ni*16+l15 (ni<2), partner ni+2.
            bool isQ = cbh < NH * HD;
            f16* dst = isQ ? (Q  + (size_t)(cbh >> 6) * SEQ * HD)
                           : (Kk + (size_t)((cbh - NH * HD) >> 6) * SEQ * HD);
            float scale = isQ ? 0.18033688011112042f : 1.0f;  // (1/8)*log2(e)
            float fr[2];
#pragma unroll
            for (int ni = 0; ni < 2; ni++)
                fr[ni] = __builtin_amdgcn_exp2f(
                    (float)(ni * 16 + l15) * -0.41524101186092029f); // -log2(1e4)/32
#pragma unroll
            for (int mi = 0; mi < 2; mi++)
#pragma unroll
                for (int r = 0; r < 4; r++) {
                    int row = rb + mi * 16 + r;
                    float pv = (float)pos[row];
#pragma unroll
                    for (int ni = 0; ni < 2; ni++) {
                        float sn, cs;
                        __sincosf(pv * fr[ni], &sn, &cs);
                        float x1 = acc[mi][ni][r], x2 = acc[mi][ni + 2][r];
                        int d = ni * 16 + l15;
                        dst[(size_t)row * HD + d]      = (f16)(scale * (x1 * cs - x2 * sn));
                        dst[(size_t)row * HD + d + 32] = (f16)(scale * (x2 * cs + x1 * sn));
                    }
                }
        } else {
            // ---- V^T with mask folded in: VT[c2][s] = v * exp2(mask[s]*log2e).
            const float LOG2E = 1.4426950408889634f;
#pragma unroll
            for (int mi = 0; mi < 2; mi++) {
                float4 mv = *(const float4*)(mask + rb + mi * 16);
                float em[4];
#pragma unroll
                for (int r = 0; r < 4; r++)
                    em[r] = __builtin_amdgcn_exp2f((&mv.x)[r] * LOG2E);
#pragma unroll
                for (int ni = 0; ni < 4; ni++) {
                    int c2 = cbh - (NH + NKV) * HD + ni * 16 + l15;
                    f16x4 v4 = { (f16)(acc[mi][ni][0] * em[0]),
                                 (f16)(acc[mi][ni][1] * em[1]),
                                 (f16)(acc[mi][ni][2] * em[2]),
                                 (f16)(acc[mi][ni][3] * em[3]) };
                    *(f16x4*)(VT + (size_t)c2 * SEQ + rb + mi * 16) = v4;
                }
            }
        }
    } else {
#pragma unroll
        for (int mi = 0; mi < 2; mi++)
#pragma unroll
            for (int ni = 0; ni < 4; ni++)
#pragma unroll
                for (int r = 0; r < 4; r++)
                    Cf[(size_t)(rb + mi * 16 + r) * N + cbh + ni * 16 + l15] =
                        acc[mi][ni][r];
    }
}

// ---------------- fused flash attention, P in registers, direct ctx ----------------
// grid (SEQ/128, NH) = 512 blocks, 4 waves; wave owns 32 q-rows, full 2048 keys.
// K staged with PERMUTED key rows so the S^T C-layout IS the PV B-operand
// layout (P never touches LDS). Mask folded into V (GEMM epilogue); l computed
// by an em-fragment MFMA (l[q] = sum_k em[k] P[k][q]) -> no per-score VALU for
// mask/l, no epilogue shuffles. LDS = 36 KB.
__global__ __launch_bounds__(256)
void attn_fused(const f16* __restrict__ Qb, const f16* __restrict__ Kb,
                const f16* __restrict__ VTb, const float* __restrict__ mask,
                f16* __restrict__ ctx) {
    __shared__ f16 Ks[2][64 * 64];
    __shared__ f16 Vs[2][64 * 64];
    __shared__ f16 Em[SEQ];

    int t = threadIdx.x, w = t >> 6, lane = t & 63, quad = lane >> 4, l15 = lane & 15;
    int h = blockIdx.y, kvh = h >> 2;
    int qbase = blockIdx.x * 128 + w * 32;
    const f16* Qh = Qb  + (size_t)h   * SEQ * HD;
    const f16* Kh = Kb  + (size_t)kvh * SEQ * HD;
    const f16* Vh = VTb + (size_t)kvh * HD * SEQ;
    int sw = l15 & 7;
    const float LOG2E = 1.4426950408889634f;

    // ---- stage em = exp2(mask*log2e) into LDS (once per block) ----
    {
        int idx = t * 8;
        float4 ma = *(const float4*)(mask + idx);
        float4 mb = *(const float4*)(mask + idx + 4);
        f16x8 e;
        e[0] = (f16)__builtin_amdgcn_exp2f(ma.x * LOG2E);
        e[1] = (f16)__builtin_amdgcn_exp2f(ma.y * LOG2E);
        e[2] = (f16)__builtin_amdgcn_exp2f(ma.z * LOG2E);
        e[3] = (f16)__builtin_amdgcn_exp2f(ma.w * LOG2E);
        e[4] = (f16)__builtin_amdgcn_exp2f(mb.x * LOG2E);
        e[5] = (f16)__builtin_amdgcn_exp2f(mb.y * LOG2E);
        e[6] = (f16)__builtin_amdgcn_exp2f(mb.z * LOG2E);
        e[7] = (f16)__builtin_amdgcn_exp2f(mb.w * LOG2E);
        *(f16x8*)(&Em[idx]) = e;
    }

    // staging lane geometry: 8 rows x 8 chunks per async16, XOR-swizzled chunks.
    // K rows permuted: LDS row rr = w*16 + r8 holds key g = 32*(w>>1) + 4*(w&1)
    // + 8*(r8>>2) + (r8&3); second async16 covers rr+8 -> g+16.
    int r8 = lane >> 3;
    int cc = (lane & 7) ^ r8;
    int gk = 32 * (w >> 1) + 4 * (w & 1) + 8 * (r8 >> 2) + (r8 & 3);
    const f16* kg0 = Kh + (size_t)gk * HD + cc * 8;
    const f16* kg1 = kg0 + (size_t)16 * HD;
    const f16* vg0 = Vh + (size_t)(w * 16 + r8) * SEQ + cc * 8;
    const f16* vg1 = vg0 + 8 * SEQ;
    int lr0 = (w * 16) * 64, lr1 = (w * 16 + 8) * 64;

    async16(kg0, &Ks[0][lr0]);
    async16(kg1, &Ks[0][lr1]);
    async16(vg0, &Vs[0][lr0]);
    async16(vg1, &Vs[0][lr1]);

    // ---- Q fragments (persistent): B-operand of S^T, n = q ----
    f16x8 bq[2][2];
#pragma unroll
    for (int qg = 0; qg < 2; qg++)
#pragma unroll
        for (int ks = 0; ks < 2; ks++)
            bq[qg][ks] = *(const f16x8*)(Qh + (size_t)(qbase + qg * 16 + l15) * HD
                                            + ks * 32 + quad * 8);

    f32x4 o[4][2] = {};          // O^T: [d-tile][q-group]
    f32x4 ol[2]   = {};          // l accumulator (all 4 rows identical)

    __syncthreads();
    int b = 0;

    for (int ktl = 0; ktl < SEQ / 64; ktl++) {
        if (ktl + 1 < SEQ / 64) {
            kg0 += 64 * HD; kg1 += 64 * HD; vg0 += 64; vg1 += 64;
            async16(kg0, &Ks[b ^ 1][lr0]);
            async16(kg1, &Ks[b ^ 1][lr1]);
            async16(vg0, &Vs[b ^ 1][lr0]);
            async16(vg1, &Vs[b ^ 1][lr1]);
        }
        const f16* Kb_ = &Ks[b][0];
        const f16* Vb_ = &Vs[b][0];

        // ---- S^T = K @ Q^T (keys in permuted order) ----
        f32x4 st[4][2] = {};
#pragma unroll
        for (int ni = 0; ni < 4; ni++) {
            const f16* kr = Kb_ + (ni * 16 + l15) * 64;
            f16x8 ak0 = *(const f16x8*)(kr + (quad ^ sw) * 8);
            f16x8 ak1 = *(const f16x8*)(kr + ((4 | quad) ^ sw) * 8);
#pragma unroll
            for (int qg = 0; qg < 2; qg++) {
                st[ni][qg] = mfma_16x16x32(ak0, bq[qg][0], st[ni][qg]);
                st[ni][qg] = mfma_16x16x32(ak1, bq[qg][1], st[ni][qg]);
            }
        }
        // ---- p = exp2(s) (mask lives in V), pack P into PV B-frags ----
        f16x8 pb[2][2];   // [qg][ks]
#pragma unroll
        for (int ni = 0; ni < 4; ni++)
#pragma unroll
            for (int qg = 0; qg < 2; qg++)
#pragma unroll
                for (int r = 0; r < 4; r++)
                    pb[qg][ni >> 1][(ni & 1) * 4 + r] =
                        (f16)__builtin_amdgcn_exp2f(st[ni][qg][r]);
        // ---- l += em-row @ P (MFMA; every output row = l[q]) ----
        f16x8 em0 = *(const f16x8*)(&Em[ktl * 64 + quad * 8]);
        f16x8 em1 = *(const f16x8*)(&Em[ktl * 64 + 32 + quad * 8]);
#pragma unroll
        for (int qg = 0; qg < 2; qg++) {
            ol[qg] = mfma_16x16x32(em0, pb[qg][0], ol[qg]);
            ol[qg] = mfma_16x16x32(em1, pb[qg][1], ol[qg]);
        }
        // ---- O^T += V^T @ P : A = V^T rows d (em-scaled), B = pb ----
#pragma unroll
        for (int dt = 0; dt < 4; dt++) {
            const f16* vr = Vb_ + (dt * 16 + l15) * 64;
            f16x8 av0 = *(const f16x8*)(vr + (quad ^ sw) * 8);
            f16x8 av1 = *(const f16x8*)(vr + ((4 | quad) ^ sw) * 8);
#pragma unroll
            for (int qg = 0; qg < 2; qg++) {
                o[dt][qg] = mfma_16x16x32(av0, pb[qg][0], o[dt][qg]);
                o[dt][qg] = mfma_16x16x32(av1, pb[qg][1], o[dt][qg]);
            }
        }
        __syncthreads();
        b ^= 1;
    }

    // ---- l already in-lane: ol[qg] rows identical = l[q = qg*16+l15] ----
    float linv[2] = { 1.0f / ol[0][0], 1.0f / ol[1][0] };

    // ---- ctx[row][h*64+d]: lane holds d = dt*16+quad*4+r, q = qg*16+l15 ----
#pragma unroll
    for (int dt = 0; dt < 4; dt++)
#pragma unroll
        for (int qg = 0; qg < 2; qg++) {
            f16x4 v4 = { (f16)(o[dt][qg][0] * linv[qg]),
                         (f16)(o[dt][qg][1] * linv[qg]),
                         (f16)(o[dt][qg][2] * linv[qg]),
                         (f16)(o[dt][qg][3] * linv[qg]) };
            *(f16x4*)(ctx + (size_t)(qbase + qg * 16 + l15) * (NH * HD)
                          + h * 64 + dt * 16 + quad * 4) = v4;
        }
}

// ---------------- launch ----------------
extern "C" void kernel_launch(void* const* d_in, const int* in_sizes, int n_in,
                              void* d_out, int out_size, void* d_ws, size_t ws_size,
                              hipStream_t stream) {
    const float* x    = (const float*)d_in[0];
    const float* mask = (const float*)d_in[1];
    const int*   pos  = (const int*)  d_in[2];
    const float* wq   = (const float*)d_in[3];
    const float* wk   = (const float*)d_in[4];
    const float* wv   = (const float*)d_in[5];
    const float* wo   = (const float*)d_in[6];
    float* out = (float*)d_out;

    char* ws = (char*)d_ws;
    // xb [0,8M) dead after QKV -> ctx reuses [0,8M).
    // Wcat [8M,20M), woT [20M,28M), Qb [28M,36M), Kb [36M,38M), VTb [38M,40M)
    f16* xb   = (f16*)(ws);
    f16* ctx  = (f16*)(ws);
    f16* Wcat = (f16*)(ws + ((size_t)8  << 20));
    f16* woT  = (f16*)(ws + ((size_t)20 << 20));
    f16* Qb   = (f16*)(ws + ((size_t)28 << 20));
    f16* Kb   = (f16*)(ws + ((size_t)36 << 20));
    f16* VTb  = (f16*)(ws + ((size_t)38 << 20));

    prep_all<<<dim3(64, 64, 5), dim3(32, 8), 0, stream>>>(
        x, wq, wk, wv, wo, xb, Wcat, woT);

    // fused Q/K/V projection + RoPE + mask-folded V: C[2048,3072] = xb @ Wcat^T
    gemm_bt<0><<<dim3(3072 / 128, 2048 / 64), 256, 0, stream>>>(
        xb, Wcat, nullptr, Qb, Kb, VTb, pos, mask, 3072, 2048);

    attn_fused<<<dim3(SEQ / 128, NH), 256, 0, stream>>>(
        Qb, Kb, VTb, mask, ctx);

    // out = ctx @ wo (fp32 direct)
    gemm_bt<1><<<dim3(2048 / 128, 2048 / 64), 256, 0, stream>>>(
        ctx, woT, out, nullptr, nullptr, nullptr, nullptr, nullptr, 2048, 2048);
}

// Round 11
// 220.407 us; speedup vs baseline: 1.2751x; 1.0592x over previous
//
#include <hip/hip_runtime.h>

#define SEQ 2048
#define HID 2048
#define NH  32
#define NKV 8
#define HD  64

typedef _Float16 f16;
typedef __attribute__((ext_vector_type(4))) _Float16 f16x4;
typedef __attribute__((ext_vector_type(8))) _Float16 f16x8;
typedef __attribute__((ext_vector_type(2))) __fp16   h16x2;
typedef __attribute__((ext_vector_type(4))) float    f32x4;

__device__ __forceinline__ f32x4 mfma_16x16x32(f16x8 a, f16x8 b, f32x4 c) {
    return __builtin_amdgcn_mfma_f32_16x16x32_f16(a, b, c, 0, 0, 0);
}

// async global->LDS, 16B per lane. Global address is PER-LANE (gather);
// LDS dest is wave-uniform base + lane*16 (contiguous).
__device__ __forceinline__ void async16(const void* g, void* l) {
    __builtin_amdgcn_global_load_lds(
        (const __attribute__((address_space(1))) void*)g,
        (__attribute__((address_space(3))) void*)l,
        16, 0, 0);
}

// ---------------- prep: 4 weight transposes + x cvt in ONE launch ----------------
__global__ void prep_all(const float* __restrict__ x,
                         const float* __restrict__ wq, const float* __restrict__ wk,
                         const float* __restrict__ wv, const float* __restrict__ wo,
                         f16* __restrict__ xb,
                         f16* __restrict__ Wcat, f16* __restrict__ woT) {
    __shared__ float tile[32][33];
    int z = blockIdx.z;
    int tx = threadIdx.x, ty = threadIdx.y;
    if (z == 4) {   // cvt: 2048*2048 flat
        int idx = (blockIdx.y * 64 + blockIdx.x) * 256 + ty * 32 + tx;
        int i = idx * 4;
        float4 v = *(const float4*)(x + i);
        f16x4 o = { (f16)v.x, (f16)v.y, (f16)v.z, (f16)v.w };
        *(f16x4*)(xb + i) = o;
        return;
    }
    const float* src; f16* dst; int C;
    if      (z == 0) { src = wq; dst = Wcat;                         C = 2048; }
    else if (z == 1) { src = wk; dst = Wcat + (size_t)2048 * 2048;   C = 512;  }
    else if (z == 2) { src = wv; dst = Wcat + (size_t)2560 * 2048;   C = 512;  }
    else             { src = wo; dst = woT;                          C = 2048; }
    int c0 = blockIdx.x * 32, r0 = blockIdx.y * 32;
    if (c0 >= C) return;
#pragma unroll
    for (int i = 0; i < 32; i += 8)
        tile[ty + i][tx] = src[(size_t)(r0 + ty + i) * C + c0 + tx];
    __syncthreads();
#pragma unroll
    for (int i = 0; i < 32; i += 8)
        dst[(size_t)(c0 + ty + i) * 2048 + r0 + tx] = (f16)tile[tx][ty + i];
}

// ---------------- GEMM: C[M,N] = A[M,K] @ BT[N,K]^T ----------------
// 64(M) x 128(N) tile, BK=64 (32 barriers), 4 waves 2x2, dbuf staging with
// XOR-swizzled k-chunks (conflict-free b128 reads; same scheme as attn).
// MODE 0: fused QKV epilogue + RoPE; V^T scaled by em[s]=exp2(mask[s]*log2e).
// MODE 1: fp32 row-major direct into Cf.
template <int MODE>
__global__ __launch_bounds__(256)
void gemm_bt(const f16* __restrict__ A, const f16* __restrict__ BT,
             float* __restrict__ Cf, f16* __restrict__ Q, f16* __restrict__ Kk,
             f16* __restrict__ VT, const int* __restrict__ pos,
             const float* __restrict__ mask, int N, int K) {
    __shared__ f16 As[2][64 * 64];    // [row][k-chunk swizzled]
    __shared__ f16 Bs[2][128 * 64];
    int t = threadIdx.x;
    int w = t >> 6, lane = t & 63, quad = lane >> 4, l15 = lane & 15;
    int wm = w >> 1, wn = w & 1;
    int m0 = blockIdx.y * 64, n0 = blockIdx.x * 128;
    int sw = l15 & 7;

    int r8 = lane >> 3;            // row within 8-row staging group
    int cc = (lane & 7) ^ r8;      // XOR-swizzled global k-chunk
    const f16* Ag0 = A  + (size_t)(m0 + w * 16 + r8) * K + cc * 8;
    const f16* Ag1 = Ag0 + (size_t)8 * K;
    const f16* Bg  = BT + (size_t)(n0 + w * 32 + r8) * K + cc * 8;

    f32x4 acc[2][4] = {};

    // stage tile 0
    async16(Ag0, &As[0][w * 1024]);
    async16(Ag1, &As[0][w * 1024 + 512]);
#pragma unroll
    for (int g = 0; g < 4; g++)
        async16(Bg + (size_t)(8 * g) * K, &Bs[0][w * 2048 + g * 512]);
    __syncthreads();

    int b = 0;
    for (int kt = 64; kt <= K; kt += 64) {
        if (kt < K) {
            async16(Ag0 + kt, &As[b ^ 1][w * 1024]);
            async16(Ag1 + kt, &As[b ^ 1][w * 1024 + 512]);
#pragma unroll
            for (int g = 0; g < 4; g++)
                async16(Bg + (size_t)(8 * g) * K + kt, &Bs[b ^ 1][w * 2048 + g * 512]);
        }
        f16x8 af[2][2], bf[4][2];
#pragma unroll
        for (int mi = 0; mi < 2; mi++) {
            int row = wm * 32 + mi * 16 + l15;
#pragma unroll
            for (int kh = 0; kh < 2; kh++)
                af[mi][kh] = *(const f16x8*)(&As[b][row * 64 + ((kh * 4 + quad) ^ sw) * 8]);
        }
#pragma unroll
        for (int ni = 0; ni < 4; ni++) {
            int row = wn * 64 + ni * 16 + l15;
#pragma unroll
            for (int kh = 0; kh < 2; kh++)
                bf[ni][kh] = *(const f16x8*)(&Bs[b][row * 64 + ((kh * 4 + quad) ^ sw) * 8]);
        }
#pragma unroll
        for (int mi = 0; mi < 2; mi++)
#pragma unroll
            for (int ni = 0; ni < 4; ni++) {
                acc[mi][ni] = mfma_16x16x32(af[mi][0], bf[ni][0], acc[mi][ni]);
                acc[mi][ni] = mfma_16x16x32(af[mi][1], bf[ni][1], acc[mi][ni]);
            }
        __syncthreads();
        b ^= 1;
    }

    int rb  = m0 + wm * 32 + quad * 4;
    int cbh = n0 + wn * 64;          // 64-aligned: one head per wave column
    if (MODE == 0) {
        if (cbh < (NH + NKV) * HD) {
            // ---- Q or K head: RoPE fused. d = ni*16+l15 (ni<2), partner ni+2.
            bool isQ = cbh < NH * HD;
            f16* dst = isQ ? (Q  + (size_t)(cbh >> 6) * SEQ * HD)
                           : (Kk + (size_t)((cbh - NH * HD) >> 6) * SEQ * HD);
            float scale = isQ ? 0.18033688011112042f : 1.0f;  // (1/8)*log2(e)
            float fr[2];
#pragma unroll
            for (int ni = 0; ni < 2; ni++)
                fr[ni] = __builtin_amdgcn_exp2f(
                    (float)(ni * 16 + l15) * -0.41524101186092029f); // -log2(1e4)/32
#pragma unroll
            for (int mi = 0; mi < 2; mi++)
#pragma unroll
                for (int r = 0; r < 4; r++) {
                    int row = rb + mi * 16 + r;
                    float pv = (float)pos[row];
#pragma unroll
                    for (int ni = 0; ni < 2; ni++) {
                        float sn, cs;
                        __sincosf(pv * fr[ni], &sn, &cs);
                        float x1 = acc[mi][ni][r], x2 = acc[mi][ni + 2][r];
                        int d = ni * 16 + l15;
                        dst[(size_t)row * HD + d]      = (f16)(scale * (x1 * cs - x2 * sn));
                        dst[(size_t)row * HD + d + 32] = (f16)(scale * (x2 * cs + x1 * sn));
                    }
                }
        } else {
            // ---- V^T with mask folded in: VT[c2][s] = v * exp2(mask[s]*log2e).
            const float LOG2E = 1.4426950408889634f;
#pragma unroll
            for (int mi = 0; mi < 2; mi++) {
                float4 mv = *(const float4*)(mask + rb + mi * 16);
                float em[4];
#pragma unroll
                for (int r = 0; r < 4; r++)
                    em[r] = __builtin_amdgcn_exp2f((&mv.x)[r] * LOG2E);
#pragma unroll
                for (int ni = 0; ni < 4; ni++) {
                    int c2 = cbh - (NH + NKV) * HD + ni * 16 + l15;
                    f16x4 v4;
                    ((h16x2*)&v4)[0] = __builtin_amdgcn_cvt_pkrtz(
                        acc[mi][ni][0] * em[0], acc[mi][ni][1] * em[1]);
                    ((h16x2*)&v4)[1] = __builtin_amdgcn_cvt_pkrtz(
                        acc[mi][ni][2] * em[2], acc[mi][ni][3] * em[3]);
                    *(f16x4*)(VT + (size_t)c2 * SEQ + rb + mi * 16) = v4;
                }
            }
        }
    } else {
#pragma unroll
        for (int mi = 0; mi < 2; mi++)
#pragma unroll
            for (int ni = 0; ni < 4; ni++)
#pragma unroll
                for (int r = 0; r < 4; r++)
                    Cf[(size_t)(rb + mi * 16 + r) * N + cbh + ni * 16 + l15] =
                        acc[mi][ni][r];
    }
}

// ---------------- fused flash attention, P in registers, direct ctx ----------------
// grid (SEQ/128, NH) = 512 blocks, 4 waves; wave owns 32 q-rows, full 2048 keys.
// K staged with PERMUTED key rows so the S^T C-layout IS the PV B-operand
// layout (P never touches LDS). Mask folded into V; l via em-fragment MFMA.
// P packing via v_cvt_pkrtz (full-rate). LDS = 36 KB.
__global__ __launch_bounds__(256)
void attn_fused(const f16* __restrict__ Qb, const f16* __restrict__ Kb,
                const f16* __restrict__ VTb, const float* __restrict__ mask,
                f16* __restrict__ ctx) {
    __shared__ f16 Ks[2][64 * 64];
    __shared__ f16 Vs[2][64 * 64];
    __shared__ f16 Em[SEQ];

    int t = threadIdx.x, w = t >> 6, lane = t & 63, quad = lane >> 4, l15 = lane & 15;
    int h = blockIdx.y, kvh = h >> 2;
    int qbase = blockIdx.x * 128 + w * 32;
    const f16* Qh = Qb  + (size_t)h   * SEQ * HD;
    const f16* Kh = Kb  + (size_t)kvh * SEQ * HD;
    const f16* Vh = VTb + (size_t)kvh * HD * SEQ;
    int sw = l15 & 7;
    const float LOG2E = 1.4426950408889634f;

    // ---- stage em = exp2(mask*log2e) into LDS (once per block) ----
    {
        int idx = t * 8;
        float4 ma = *(const float4*)(mask + idx);
        float4 mb = *(const float4*)(mask + idx + 4);
        f16x8 e;
        ((h16x2*)&e)[0] = __builtin_amdgcn_cvt_pkrtz(
            __builtin_amdgcn_exp2f(ma.x * LOG2E), __builtin_amdgcn_exp2f(ma.y * LOG2E));
        ((h16x2*)&e)[1] = __builtin_amdgcn_cvt_pkrtz(
            __builtin_amdgcn_exp2f(ma.z * LOG2E), __builtin_amdgcn_exp2f(ma.w * LOG2E));
        ((h16x2*)&e)[2] = __builtin_amdgcn_cvt_pkrtz(
            __builtin_amdgcn_exp2f(mb.x * LOG2E), __builtin_amdgcn_exp2f(mb.y * LOG2E));
        ((h16x2*)&e)[3] = __builtin_amdgcn_cvt_pkrtz(
            __builtin_amdgcn_exp2f(mb.z * LOG2E), __builtin_amdgcn_exp2f(mb.w * LOG2E));
        *(f16x8*)(&Em[idx]) = e;
    }

    // staging lane geometry: 8 rows x 8 chunks per async16, XOR-swizzled chunks.
    // K rows permuted: LDS row rr = w*16 + r8 holds key g = 32*(w>>1) + 4*(w&1)
    // + 8*(r8>>2) + (r8&3); second async16 covers rr+8 -> g+16.
    int r8 = lane >> 3;
    int cc = (lane & 7) ^ r8;
    int gk = 32 * (w >> 1) + 4 * (w & 1) + 8 * (r8 >> 2) + (r8 & 3);
    const f16* kg0 = Kh + (size_t)gk * HD + cc * 8;
    const f16* kg1 = kg0 + (size_t)16 * HD;
    const f16* vg0 = Vh + (size_t)(w * 16 + r8) * SEQ + cc * 8;
    const f16* vg1 = vg0 + 8 * SEQ;
    int lr0 = (w * 16) * 64, lr1 = (w * 16 + 8) * 64;

    async16(kg0, &Ks[0][lr0]);
    async16(kg1, &Ks[0][lr1]);
    async16(vg0, &Vs[0][lr0]);
    async16(vg1, &Vs[0][lr1]);

    // ---- Q fragments (persistent): B-operand of S^T, n = q ----
    f16x8 bq[2][2];
#pragma unroll
    for (int qg = 0; qg < 2; qg++)
#pragma unroll
        for (int ks = 0; ks < 2; ks++)
            bq[qg][ks] = *(const f16x8*)(Qh + (size_t)(qbase + qg * 16 + l15) * HD
                                            + ks * 32 + quad * 8);

    f32x4 o[4][2] = {};          // O^T: [d-tile][q-group]
    f32x4 ol[2]   = {};          // l accumulator (all 4 rows identical)

    int c0 = (quad ^ sw) * 8, c1 = ((4 | quad) ^ sw) * 8;

    __syncthreads();
    int b = 0;

    for (int ktl = 0; ktl < SEQ / 64; ktl++) {
        if (ktl + 1 < SEQ / 64) {
            kg0 += 64 * HD; kg1 += 64 * HD; vg0 += 64; vg1 += 64;
            async16(kg0, &Ks[b ^ 1][lr0]);
            async16(kg1, &Ks[b ^ 1][lr1]);
            async16(vg0, &Vs[b ^ 1][lr0]);
            async16(vg1, &Vs[b ^ 1][lr1]);
        }
        const f16* Kb_ = &Ks[b][0];
        const f16* Vb_ = &Vs[b][0];

        // ---- S^T = K @ Q^T (keys in permuted order) ----
        f32x4 st[4][2] = {};
#pragma unroll
        for (int ni = 0; ni < 4; ni++) {
            const f16* kr = Kb_ + (ni * 16 + l15) * 64;
            f16x8 ak0 = *(const f16x8*)(kr + c0);
            f16x8 ak1 = *(const f16x8*)(kr + c1);
#pragma unroll
            for (int qg = 0; qg < 2; qg++) {
                st[ni][qg] = mfma_16x16x32(ak0, bq[qg][0], st[ni][qg]);
                st[ni][qg] = mfma_16x16x32(ak1, bq[qg][1], st[ni][qg]);
            }
        }
        // ---- p = exp2(s) (mask lives in V); pack via cvt_pkrtz (full-rate) ----
        f16x8 pb[2][2];   // [qg][ks]
#pragma unroll
        for (int ni = 0; ni < 4; ni++)
#pragma unroll
            for (int qg = 0; qg < 2; qg++) {
                h16x2 lo = __builtin_amdgcn_cvt_pkrtz(
                    __builtin_amdgcn_exp2f(st[ni][qg][0]),
                    __builtin_amdgcn_exp2f(st[ni][qg][1]));
                h16x2 hi = __builtin_amdgcn_cvt_pkrtz(
                    __builtin_amdgcn_exp2f(st[ni][qg][2]),
                    __builtin_amdgcn_exp2f(st[ni][qg][3]));
                ((h16x2*)&pb[qg][ni >> 1])[(ni & 1) * 2]     = lo;
                ((h16x2*)&pb[qg][ni >> 1])[(ni & 1) * 2 + 1] = hi;
            }
        // ---- l += em-row @ P (MFMA; every output row = l[q]) ----
        f16x8 em0 = *(const f16x8*)(&Em[ktl * 64 + quad * 8]);
        f16x8 em1 = *(const f16x8*)(&Em[ktl * 64 + 32 + quad * 8]);
#pragma unroll
        for (int qg = 0; qg < 2; qg++) {
            ol[qg] = mfma_16x16x32(em0, pb[qg][0], ol[qg]);
            ol[qg] = mfma_16x16x32(em1, pb[qg][1], ol[qg]);
        }
        // ---- O^T += V^T @ P : A = V^T rows d (em-scaled), B = pb ----
#pragma unroll
        for (int dt = 0; dt < 4; dt++) {
            const f16* vr = Vb_ + (dt * 16 + l15) * 64;
            f16x8 av0 = *(const f16x8*)(vr + c0);
            f16x8 av1 = *(const f16x8*)(vr + c1);
#pragma unroll
            for (int qg = 0; qg < 2; qg++) {
                o[dt][qg] = mfma_16x16x32(av0, pb[qg][0], o[dt][qg]);
                o[dt][qg] = mfma_16x16x32(av1, pb[qg][1], o[dt][qg]);
            }
        }
        __syncthreads();
        b ^= 1;
    }

    // ---- l already in-lane: ol[qg] rows identical = l[q = qg*16+l15] ----
    float linv[2] = { 1.0f / ol[0][0], 1.0f / ol[1][0] };

    // ---- ctx[row][h*64+d]: lane holds d = dt*16+quad*4+r, q = qg*16+l15 ----
#pragma unroll
    for (int dt = 0; dt < 4; dt++)
#pragma unroll
        for (int qg = 0; qg < 2; qg++) {
            f16x4 v4;
            ((h16x2*)&v4)[0] = __builtin_amdgcn_cvt_pkrtz(
                o[dt][qg][0] * linv[qg], o[dt][qg][1] * linv[qg]);
            ((h16x2*)&v4)[1] = __builtin_amdgcn_cvt_pkrtz(
                o[dt][qg][2] * linv[qg], o[dt][qg][3] * linv[qg]);
            *(f16x4*)(ctx + (size_t)(qbase + qg * 16 + l15) * (NH * HD)
                          + h * 64 + dt * 16 + quad * 4) = v4;
        }
}

// ---------------- launch ----------------
extern "C" void kernel_launch(void* const* d_in, const int* in_sizes, int n_in,
                              void* d_out, int out_size, void* d_ws, size_t ws_size,
                              hipStream_t stream) {
    const float* x    = (const float*)d_in[0];
    const float* mask = (const float*)d_in[1];
    const int*   pos  = (const int*)  d_in[2];
    const float* wq   = (const float*)d_in[3];
    const float* wk   = (const float*)d_in[4];
    const float* wv   = (const float*)d_in[5];
    const float* wo   = (const float*)d_in[6];
    float* out = (float*)d_out;

    char* ws = (char*)d_ws;
    // xb [0,8M) dead after QKV -> ctx reuses [0,8M).
    f16* xb   = (f16*)(ws);
    f16* ctx  = (f16*)(ws);
    f16* Wcat = (f16*)(ws + ((size_t)8  << 20));
    f16* woT  = (f16*)(ws + ((size_t)20 << 20));
    f16* Qb   = (f16*)(ws + ((size_t)28 << 20));
    f16* Kb   = (f16*)(ws + ((size_t)36 << 20));
    f16* VTb  = (f16*)(ws + ((size_t)38 << 20));

    prep_all<<<dim3(64, 64, 5), dim3(32, 8), 0, stream>>>(
        x, wq, wk, wv, wo, xb, Wcat, woT);

    // fused Q/K/V projection + RoPE + mask-folded V: C[2048,3072] = xb @ Wcat^T
    gemm_bt<0><<<dim3(3072 / 128, 2048 / 64), 256, 0, stream>>>(
        xb, Wcat, nullptr, Qb, Kb, VTb, pos, mask, 3072, 2048);

    attn_fused<<<dim3(SEQ / 128, NH), 256, 0, stream>>>(
        Qb, Kb, VTb, mask, ctx);

    // out = ctx @ wo (fp32 direct)
    gemm_bt<1><<<dim3(2048 / 128, 2048 / 64), 256, 0, stream>>>(
        ctx, woT, out, nullptr, nullptr, nullptr, nullptr, nullptr, 2048, 2048);
}

// Round 12
// 206.545 us; speedup vs baseline: 1.3607x; 1.0671x over previous
//
#include <hip/hip_runtime.h>

#define SEQ 2048
#define HID 2048
#define NH  32
#define NKV 8
#define HD  64

typedef _Float16 f16;
typedef __attribute__((ext_vector_type(4))) _Float16 f16x4;
typedef __attribute__((ext_vector_type(8))) _Float16 f16x8;
typedef __attribute__((ext_vector_type(2))) __fp16   h16x2;
typedef __attribute__((ext_vector_type(4))) float    f32x4;

__device__ __forceinline__ f32x4 mfma_16x16x32(f16x8 a, f16x8 b, f32x4 c) {
    return __builtin_amdgcn_mfma_f32_16x16x32_f16(a, b, c, 0, 0, 0);
}

// async global->LDS, 16B per lane. Global address is PER-LANE (gather);
// LDS dest is wave-uniform base + lane*16 (contiguous).
__device__ __forceinline__ void async16(const void* g, void* l) {
    __builtin_amdgcn_global_load_lds(
        (const __attribute__((address_space(1))) void*)g,
        (__attribute__((address_space(3))) void*)l,
        16, 0, 0);
}

// ---------------- prep: 4 weight transposes + x cvt in ONE launch ----------------
__global__ void prep_all(const float* __restrict__ x,
                         const float* __restrict__ wq, const float* __restrict__ wk,
                         const float* __restrict__ wv, const float* __restrict__ wo,
                         f16* __restrict__ xb,
                         f16* __restrict__ Wcat, f16* __restrict__ woT) {
    __shared__ float tile[32][33];
    int z = blockIdx.z;
    int tx = threadIdx.x, ty = threadIdx.y;
    if (z == 4) {   // cvt: 2048*2048 flat
        int idx = (blockIdx.y * 64 + blockIdx.x) * 256 + ty * 32 + tx;
        int i = idx * 4;
        float4 v = *(const float4*)(x + i);
        f16x4 o = { (f16)v.x, (f16)v.y, (f16)v.z, (f16)v.w };
        *(f16x4*)(xb + i) = o;
        return;
    }
    const float* src; f16* dst; int C;
    if      (z == 0) { src = wq; dst = Wcat;                         C = 2048; }
    else if (z == 1) { src = wk; dst = Wcat + (size_t)2048 * 2048;   C = 512;  }
    else if (z == 2) { src = wv; dst = Wcat + (size_t)2560 * 2048;   C = 512;  }
    else             { src = wo; dst = woT;                          C = 2048; }
    int c0 = blockIdx.x * 32, r0 = blockIdx.y * 32;
    if (c0 >= C) return;
#pragma unroll
    for (int i = 0; i < 32; i += 8)
        tile[ty + i][tx] = src[(size_t)(r0 + ty + i) * C + c0 + tx];
    __syncthreads();
#pragma unroll
    for (int i = 0; i < 32; i += 8)
        dst[(size_t)(c0 + ty + i) * 2048 + r0 + tx] = (f16)tile[tx][ty + i];
}

// ---------------- GEMM: C[M,N] = A[M,K] @ BT[N,K]^T ----------------
// 64(M) x 128(N) tile, BK=64 (32 barriers), 4 waves 2x2, dbuf staging with
// XOR-swizzled k-chunks (conflict-free b128 reads).
// MODE 0: fused QKV epilogue + RoPE; V^T scaled by em[s]=exp2(mask[s]*log2e).
// MODE 1: fp32 row-major direct into Cf.
template <int MODE>
__global__ __launch_bounds__(256)
void gemm_bt(const f16* __restrict__ A, const f16* __restrict__ BT,
             float* __restrict__ Cf, f16* __restrict__ Q, f16* __restrict__ Kk,
             f16* __restrict__ VT, const int* __restrict__ pos,
             const float* __restrict__ mask, int N, int K) {
    __shared__ f16 As[2][64 * 64];    // [row][k-chunk swizzled]
    __shared__ f16 Bs[2][128 * 64];
    int t = threadIdx.x;
    int w = t >> 6, lane = t & 63, quad = lane >> 4, l15 = lane & 15;
    int wm = w >> 1, wn = w & 1;
    int m0 = blockIdx.y * 64, n0 = blockIdx.x * 128;
    int sw = l15 & 7;

    int r8 = lane >> 3;            // row within 8-row staging group
    int cc = (lane & 7) ^ r8;      // XOR-swizzled global k-chunk
    const f16* Ag0 = A  + (size_t)(m0 + w * 16 + r8) * K + cc * 8;
    const f16* Ag1 = Ag0 + (size_t)8 * K;
    const f16* Bg  = BT + (size_t)(n0 + w * 32 + r8) * K + cc * 8;

    f32x4 acc[2][4] = {};

    // stage tile 0
    async16(Ag0, &As[0][w * 1024]);
    async16(Ag1, &As[0][w * 1024 + 512]);
#pragma unroll
    for (int g = 0; g < 4; g++)
        async16(Bg + (size_t)(8 * g) * K, &Bs[0][w * 2048 + g * 512]);
    __syncthreads();

    int b = 0;
    for (int kt = 64; kt <= K; kt += 64) {
        if (kt < K) {
            async16(Ag0 + kt, &As[b ^ 1][w * 1024]);
            async16(Ag1 + kt, &As[b ^ 1][w * 1024 + 512]);
#pragma unroll
            for (int g = 0; g < 4; g++)
                async16(Bg + (size_t)(8 * g) * K + kt, &Bs[b ^ 1][w * 2048 + g * 512]);
        }
        f16x8 af[2][2], bf[4][2];
#pragma unroll
        for (int mi = 0; mi < 2; mi++) {
            int row = wm * 32 + mi * 16 + l15;
#pragma unroll
            for (int kh = 0; kh < 2; kh++)
                af[mi][kh] = *(const f16x8*)(&As[b][row * 64 + ((kh * 4 + quad) ^ sw) * 8]);
        }
#pragma unroll
        for (int ni = 0; ni < 4; ni++) {
            int row = wn * 64 + ni * 16 + l15;
#pragma unroll
            for (int kh = 0; kh < 2; kh++)
                bf[ni][kh] = *(const f16x8*)(&Bs[b][row * 64 + ((kh * 4 + quad) ^ sw) * 8]);
        }
#pragma unroll
        for (int mi = 0; mi < 2; mi++)
#pragma unroll
            for (int ni = 0; ni < 4; ni++) {
                acc[mi][ni] = mfma_16x16x32(af[mi][0], bf[ni][0], acc[mi][ni]);
                acc[mi][ni] = mfma_16x16x32(af[mi][1], bf[ni][1], acc[mi][ni]);
            }
        __syncthreads();
        b ^= 1;
    }

    int rb  = m0 + wm * 32 + quad * 4;
    int cbh = n0 + wn * 64;          // 64-aligned: one head per wave column
    if (MODE == 0) {
        if (cbh < (NH + NKV) * HD) {
            bool isQ = cbh < NH * HD;
            f16* dst = isQ ? (Q  + (size_t)(cbh >> 6) * SEQ * HD)
                           : (Kk + (size_t)((cbh - NH * HD) >> 6) * SEQ * HD);
            float scale = isQ ? 0.18033688011112042f : 1.0f;  // (1/8)*log2(e)
            float fr[2];
#pragma unroll
            for (int ni = 0; ni < 2; ni++)
                fr[ni] = __builtin_amdgcn_exp2f(
                    (float)(ni * 16 + l15) * -0.41524101186092029f); // -log2(1e4)/32
#pragma unroll
            for (int mi = 0; mi < 2; mi++)
#pragma unroll
                for (int r = 0; r < 4; r++) {
                    int row = rb + mi * 16 + r;
                    float pv = (float)pos[row];
#pragma unroll
                    for (int ni = 0; ni < 2; ni++) {
                        float sn, cs;
                        __sincosf(pv * fr[ni], &sn, &cs);
                        float x1 = acc[mi][ni][r], x2 = acc[mi][ni + 2][r];
                        int d = ni * 16 + l15;
                        dst[(size_t)row * HD + d]      = (f16)(scale * (x1 * cs - x2 * sn));
                        dst[(size_t)row * HD + d + 32] = (f16)(scale * (x2 * cs + x1 * sn));
                    }
                }
        } else {
            // ---- V^T with mask folded in: VT[c2][s] = v * exp2(mask[s]*log2e).
            const float LOG2E = 1.4426950408889634f;
#pragma unroll
            for (int mi = 0; mi < 2; mi++) {
                float4 mv = *(const float4*)(mask + rb + mi * 16);
                float em[4];
#pragma unroll
                for (int r = 0; r < 4; r++)
                    em[r] = __builtin_amdgcn_exp2f((&mv.x)[r] * LOG2E);
#pragma unroll
                for (int ni = 0; ni < 4; ni++) {
                    int c2 = cbh - (NH + NKV) * HD + ni * 16 + l15;
                    f16x4 v4;
                    ((h16x2*)&v4)[0] = __builtin_amdgcn_cvt_pkrtz(
                        acc[mi][ni][0] * em[0], acc[mi][ni][1] * em[1]);
                    ((h16x2*)&v4)[1] = __builtin_amdgcn_cvt_pkrtz(
                        acc[mi][ni][2] * em[2], acc[mi][ni][3] * em[3]);
                    *(f16x4*)(VT + (size_t)c2 * SEQ + rb + mi * 16) = v4;
                }
            }
        }
    } else {
#pragma unroll
        for (int mi = 0; mi < 2; mi++)
#pragma unroll
            for (int ni = 0; ni < 4; ni++)
#pragma unroll
                for (int r = 0; r < 4; r++)
                    Cf[(size_t)(rb + mi * 16 + r) * N + cbh + ni * 16 + l15] =
                        acc[mi][ni][r];
    }
}

// ---------------- fused flash attention: 8 waves, split-K(2), P in registers ----
// grid (SEQ/256, NH, 2) = 512 blocks x 512 threads = 16 waves/CU.
// Block: 8 waves x 32 q = 256 q-rows, split z owns 16 of 32 key tiles.
// Waves 0-3 stage K (permuted rows: g(rr)=k_eff), waves 4-7 stage V; all 8
// share the tile. Mask folded into V; l via em-fragment MFMA. LDS = 34 KB.
// Writes unnormalized O^T partials (f16) + l partials (f32).
__global__ __launch_bounds__(512)
void attn_fused(const f16* __restrict__ Qb, const f16* __restrict__ Kb,
                const f16* __restrict__ VTb, const float* __restrict__ mask,
                f16* __restrict__ Opart, float* __restrict__ Lpart) {
    __shared__ f16 Ks[2][64 * 64];
    __shared__ f16 Vs[2][64 * 64];
    __shared__ f16 Em[SEQ / 2];

    int t = threadIdx.x, w = t >> 6, lane = t & 63, quad = lane >> 4, l15 = lane & 15;
    int h = blockIdx.y, kvh = h >> 2, split = blockIdx.z;
    int qbase = blockIdx.x * 256 + w * 32;
    int key0  = split * (SEQ / 2);
    const f16* Qh = Qb  + (size_t)h   * SEQ * HD;
    const f16* Kh = Kb  + (size_t)kvh * SEQ * HD;
    const f16* Vh = VTb + (size_t)kvh * HD * SEQ;
    int sw = l15 & 7;
    const float LOG2E = 1.4426950408889634f;

    // ---- stage em = exp2(mask*log2e) for this split (once per block) ----
    if (t < 128) {
        int idx = t * 8;
        float4 ma = *(const float4*)(mask + key0 + idx);
        float4 mb = *(const float4*)(mask + key0 + idx + 4);
        f16x8 e;
        ((h16x2*)&e)[0] = __builtin_amdgcn_cvt_pkrtz(
            __builtin_amdgcn_exp2f(ma.x * LOG2E), __builtin_amdgcn_exp2f(ma.y * LOG2E));
        ((h16x2*)&e)[1] = __builtin_amdgcn_cvt_pkrtz(
            __builtin_amdgcn_exp2f(ma.z * LOG2E), __builtin_amdgcn_exp2f(ma.w * LOG2E));
        ((h16x2*)&e)[2] = __builtin_amdgcn_cvt_pkrtz(
            __builtin_amdgcn_exp2f(mb.x * LOG2E), __builtin_amdgcn_exp2f(mb.y * LOG2E));
        ((h16x2*)&e)[3] = __builtin_amdgcn_cvt_pkrtz(
            __builtin_amdgcn_exp2f(mb.z * LOG2E), __builtin_amdgcn_exp2f(mb.w * LOG2E));
        *(f16x8*)(&Em[idx]) = e;
    }

    // ---- staging: wave role. K waves use permuted rows (g(rr)=k_eff). ----
    int r8 = lane >> 3;
    int cc = (lane & 7) ^ r8;
    bool isK = w < 4;
    int ws = isK ? w : (w - 4);
    const f16* g0;
    long gstep;
    if (isK) {
        int gk = 32 * (ws >> 1) + 4 * (ws & 1) + 8 * (r8 >> 2) + (r8 & 3);
        g0 = Kh + (size_t)(key0 + gk) * HD + cc * 8;
        gstep = (long)16 * HD;       // second async16: keys g+16
    } else {
        g0 = Vh + (size_t)(ws * 16 + r8) * SEQ + key0 + cc * 8;
        gstep = (long)8 * SEQ;       // second async16: rows +8
    }
    const f16* g1 = g0 + gstep;
    long adv = isK ? (long)64 * HD : 64;
    int lr0 = ws * 16 * 64, lr1 = lr0 + 8 * 64;

    {
        f16* dst = isK ? &Ks[0][0] : &Vs[0][0];
        async16(g0, dst + lr0);
        async16(g1, dst + lr1);
    }

    // ---- Q fragments (persistent): B-operand of S^T, n = q ----
    f16x8 bq[2][2];
#pragma unroll
    for (int qg = 0; qg < 2; qg++)
#pragma unroll
        for (int ks = 0; ks < 2; ks++)
            bq[qg][ks] = *(const f16x8*)(Qh + (size_t)(qbase + qg * 16 + l15) * HD
                                            + ks * 32 + quad * 8);

    f32x4 o[4][2] = {};          // O^T: [d-tile][q-group]
    f32x4 ol[2]   = {};          // l accumulator (all rows identical)

    int c0 = (quad ^ sw) * 8, c1 = ((4 | quad) ^ sw) * 8;

    __syncthreads();
    int b = 0;

    for (int ktl = 0; ktl < SEQ / 128; ktl++) {
        if (ktl + 1 < SEQ / 128) {
            g0 += adv; g1 += adv;
            f16* dst = isK ? &Ks[b ^ 1][0] : &Vs[b ^ 1][0];
            async16(g0, dst + lr0);
            async16(g1, dst + lr1);
        }
        const f16* Kb_ = &Ks[b][0];
        const f16* Vb_ = &Vs[b][0];

        // ---- S^T = K @ Q^T (keys in permuted order) ----
        f32x4 st[4][2] = {};
#pragma unroll
        for (int ni = 0; ni < 4; ni++) {
            const f16* kr = Kb_ + (ni * 16 + l15) * 64;
            f16x8 ak0 = *(const f16x8*)(kr + c0);
            f16x8 ak1 = *(const f16x8*)(kr + c1);
#pragma unroll
            for (int qg = 0; qg < 2; qg++) {
                st[ni][qg] = mfma_16x16x32(ak0, bq[qg][0], st[ni][qg]);
                st[ni][qg] = mfma_16x16x32(ak1, bq[qg][1], st[ni][qg]);
            }
        }
        // ---- p = exp2(s) (mask lives in V); pack via cvt_pkrtz ----
        f16x8 pb[2][2];   // [qg][ks]
#pragma unroll
        for (int ni = 0; ni < 4; ni++)
#pragma unroll
            for (int qg = 0; qg < 2; qg++) {
                h16x2 lo = __builtin_amdgcn_cvt_pkrtz(
                    __builtin_amdgcn_exp2f(st[ni][qg][0]),
                    __builtin_amdgcn_exp2f(st[ni][qg][1]));
                h16x2 hi = __builtin_amdgcn_cvt_pkrtz(
                    __builtin_amdgcn_exp2f(st[ni][qg][2]),
                    __builtin_amdgcn_exp2f(st[ni][qg][3]));
                ((h16x2*)&pb[qg][ni >> 1])[(ni & 1) * 2]     = lo;
                ((h16x2*)&pb[qg][ni >> 1])[(ni & 1) * 2 + 1] = hi;
            }
        // ---- l += em-row @ P (MFMA; every output row = l[q]) ----
        f16x8 em0 = *(const f16x8*)(&Em[ktl * 64 + quad * 8]);
        f16x8 em1 = *(const f16x8*)(&Em[ktl * 64 + 32 + quad * 8]);
#pragma unroll
        for (int qg = 0; qg < 2; qg++) {
            ol[qg] = mfma_16x16x32(em0, pb[qg][0], ol[qg]);
            ol[qg] = mfma_16x16x32(em1, pb[qg][1], ol[qg]);
        }
        // ---- O^T += V^T @ P ----
#pragma unroll
        for (int dt = 0; dt < 4; dt++) {
            const f16* vr = Vb_ + (dt * 16 + l15) * 64;
            f16x8 av0 = *(const f16x8*)(vr + c0);
            f16x8 av1 = *(const f16x8*)(vr + c1);
#pragma unroll
            for (int qg = 0; qg < 2; qg++) {
                o[dt][qg] = mfma_16x16x32(av0, pb[qg][0], o[dt][qg]);
                o[dt][qg] = mfma_16x16x32(av1, pb[qg][1], o[dt][qg]);
            }
        }
        __syncthreads();
        b ^= 1;
    }

    // ---- l partial: all lanes hold l[q = qg*16+l15]; quad 0 writes ----
    if (quad == 0) {
#pragma unroll
        for (int qg = 0; qg < 2; qg++)
            Lpart[((size_t)split * NH + h) * SEQ + qbase + qg * 16 + l15] =
                ol[qg][0];
    }
    // ---- unnormalized O^T partial: lane d = dt*16+quad*4+r, q = qg*16+l15 ----
    f16* Op = Opart + ((size_t)split * NH + h) * SEQ * HD;
#pragma unroll
    for (int dt = 0; dt < 4; dt++)
#pragma unroll
        for (int qg = 0; qg < 2; qg++) {
            f16x4 v4;
            ((h16x2*)&v4)[0] = __builtin_amdgcn_cvt_pkrtz(o[dt][qg][0], o[dt][qg][1]);
            ((h16x2*)&v4)[1] = __builtin_amdgcn_cvt_pkrtz(o[dt][qg][2], o[dt][qg][3]);
            *(f16x4*)(Op + (size_t)(qbase + qg * 16 + l15) * HD
                         + dt * 16 + quad * 4) = v4;
        }
}

// ---------------- combine: ctx[row][h*64+d] = (O0+O1)/(l0+l1) ----------------
__global__ void attn_combine(const f16* __restrict__ O, const float* __restrict__ L,
                             f16* __restrict__ ctx) {
    int idx = blockIdx.x * 256 + threadIdx.x;   // one f16x4 per thread
    int c4  = idx & 511;
    int row = idx >> 9;
    int col = c4 * 4;
    int h   = col >> 6;
    float l = L[(size_t)h * SEQ + row] + L[(size_t)(NH + h) * SEQ + row];
    const f16* o0 = O + ((size_t)h * SEQ + row) * HD + (col & 63);
    const f16* o1 = o0 + (size_t)NH * SEQ * HD;
    f16x4 a = *(const f16x4*)o0, b = *(const f16x4*)o1;
    float inv = 1.0f / l;
    f16x4 r;
#pragma unroll
    for (int j = 0; j < 4; j++)
        r[j] = (f16)(((float)a[j] + (float)b[j]) * inv);
    *(f16x4*)(ctx + (size_t)row * (NH * HD) + col) = r;
}

// ---------------- launch ----------------
extern "C" void kernel_launch(void* const* d_in, const int* in_sizes, int n_in,
                              void* d_out, int out_size, void* d_ws, size_t ws_size,
                              hipStream_t stream) {
    const float* x    = (const float*)d_in[0];
    const float* mask = (const float*)d_in[1];
    const int*   pos  = (const int*)  d_in[2];
    const float* wq   = (const float*)d_in[3];
    const float* wk   = (const float*)d_in[4];
    const float* wv   = (const float*)d_in[5];
    const float* wo   = (const float*)d_in[6];
    float* out = (float*)d_out;

    char* ws = (char*)d_ws;
    // phase 1-2: xb [0,8M), Wcat [8,20M), woT [20,28M), Qb [28,36M),
    //            Kb [36,38M), VTb [38,40M)
    // phase 3:   Opart [0,16M) (xb/Wcat dead), Lpart [16,16.5M)
    // phase 4:   ctx [28,36M) (Qb dead), woT still live
    f16*   xb    = (f16*)(ws);
    f16*   Wcat  = (f16*)(ws + ((size_t)8  << 20));
    f16*   woT   = (f16*)(ws + ((size_t)20 << 20));
    f16*   Qb    = (f16*)(ws + ((size_t)28 << 20));
    f16*   Kb    = (f16*)(ws + ((size_t)36 << 20));
    f16*   VTb   = (f16*)(ws + ((size_t)38 << 20));
    f16*   Opart = (f16*)(ws);
    float* Lpart = (float*)(ws + ((size_t)16 << 20));
    f16*   ctx   = (f16*)(ws + ((size_t)28 << 20));

    prep_all<<<dim3(64, 64, 5), dim3(32, 8), 0, stream>>>(
        x, wq, wk, wv, wo, xb, Wcat, woT);

    // fused Q/K/V projection + RoPE + mask-folded V: C[2048,3072] = xb @ Wcat^T
    gemm_bt<0><<<dim3(3072 / 128, 2048 / 64), 256, 0, stream>>>(
        xb, Wcat, nullptr, Qb, Kb, VTb, pos, mask, 3072, 2048);

    attn_fused<<<dim3(SEQ / 256, NH, 2), 512, 0, stream>>>(
        Qb, Kb, VTb, mask, Opart, Lpart);
    attn_combine<<<SEQ * NH * HD / 4 / 256, 256, 0, stream>>>(Opart, Lpart, ctx);

    // out = ctx @ wo (fp32 direct)
    gemm_bt<1><<<dim3(2048 / 128, 2048 / 64), 256, 0, stream>>>(
        ctx, woT, out, nullptr, nullptr, nullptr, nullptr, nullptr, 2048, 2048);
}